// Round 2
// baseline (3821.014 us; speedup 1.0000x reference)
//
#include <hip/hip_runtime.h>
#include <hip/hip_bf16.h>
#include <math.h>

#define HW 4096
typedef __hip_bfloat16 bf16;

// ======================= generic 1x1-conv GEMM =======================
// out[b, oc, n] = epilogue( sum_ic W[oc,ic] * f(X[b, ic, n]) )
// f: optional (+ add_row[ic,y] + add_col[ic,x]) then optional relu
// epilogue 0: scale*acc+bias            (scale/bias nullable)
// epilogue 1: sigmoid(scale*acc+bias) * (s2[oc]*mul[b,oc,n] + b2[oc])
__global__ __launch_bounds__(256) void gemm1x1(
    const void* __restrict__ X, long x_b, int in_bf16,
    const float* __restrict__ W,
    const float* __restrict__ scale, const float* __restrict__ bias,
    void* __restrict__ out, long o_b, int out_bf16,
    int OC, int IC, int NP,
    int relu_in,
    const float* __restrict__ add_row, const float* __restrict__ add_col, long ar_b,
    int epi_mode, const float* __restrict__ mul_src, long mul_b,
    const float* __restrict__ s2, const float* __restrict__ b2)
{
    __shared__ __align__(16) float As[16][68];
    __shared__ __align__(16) float Bs[16][64];
    int b  = blockIdx.z;
    int oc0 = blockIdx.y * 64;
    int n0  = blockIdx.x * 64;
    int tid = threadIdx.x;
    int tx = tid & 15, ty = tid >> 4;
    float acc[4][4] = {};
    int y = n0 >> 6;   // image row when NP==4096 (tiles are 64-aligned)

    for (int k0 = 0; k0 < IC; k0 += 16) {
#pragma unroll
        for (int l = 0; l < 4; l++) {
            int e = tid + l * 256;
            int oc = e >> 4, kk = e & 15;
            As[kk][oc] = W[(long)(oc0 + oc) * IC + (k0 + kk)];
        }
#pragma unroll
        for (int l = 0; l < 4; l++) {
            int e = tid + l * 256;
            int kk = e >> 6, n = e & 63;
            int ic = k0 + kk;
            long xi = (long)b * x_b + (long)ic * NP + (n0 + n);
            float v = in_bf16 ? __bfloat162float(((const bf16*)X)[xi])
                              : ((const float*)X)[xi];
            if (add_row)
                v += add_row[(long)b * ar_b + ic * 64 + y]
                   + add_col[(long)b * ar_b + ic * 64 + n];
            if (relu_in) v = fmaxf(v, 0.f);
            Bs[kk][n] = v;
        }
        __syncthreads();
#pragma unroll
        for (int kk = 0; kk < 16; kk++) {
            float a[4], bv[4];
            *(float4*)a  = *(const float4*)&As[kk][ty * 4];
            *(float4*)bv = *(const float4*)&Bs[kk][tx * 4];
#pragma unroll
            for (int i = 0; i < 4; i++)
#pragma unroll
                for (int j = 0; j < 4; j++)
                    acc[i][j] = fmaf(a[i], bv[j], acc[i][j]);
        }
        __syncthreads();
    }

#pragma unroll
    for (int i = 0; i < 4; i++) {
        int oc = oc0 + ty * 4 + i;
        float s  = scale ? scale[oc] : 1.f;
        float bb = bias  ? bias[oc]  : 0.f;
#pragma unroll
        for (int j = 0; j < 4; j++) {
            int n = n0 + tx * 4 + j;
            float v = fmaf(s, acc[i][j], bb);
            long oidx = (long)b * o_b + (long)oc * NP + n;
            if (epi_mode == 1) {
                float m = fmaf(s2[oc], mul_src[(long)b * mul_b + (long)oc * NP + n], b2[oc]);
                v = m / (1.f + __expf(-v));
            }
            if (out_bf16) ((bf16*)out)[oidx] = __float2bfloat16(v);
            else          ((float*)out)[oidx] = v;
        }
    }
}

// ===== fused: pw 1x1 GEMM whose B input = relu(bn_dw(dwconv3x3(qkv0))) =====
// qkv0 bf16 (B,1024,64,64); w_pw (256,1024); out raw fp32 (B,256,4096)
__global__ __launch_bounds__(256) void pw_dw_gemm(
    const bf16* __restrict__ qkv0, const float* __restrict__ w_pw,
    const float* __restrict__ w_dw, const float* __restrict__ s_dw,
    const float* __restrict__ b_dw, float* __restrict__ out)
{
    __shared__ __align__(16) float As[16][68];
    __shared__ __align__(16) float Bs[16][64];
    __shared__ float Xr[48][64];     // 16 ch x 3 rows
    int b = blockIdx.z, oc0 = blockIdx.y * 64, y = blockIdx.x;
    const bf16* Qb = qkv0 + (long)b * 1024 * HW;
    int tid = threadIdx.x, tx = tid & 15, ty = tid >> 4;
    float acc[4][4] = {};

    for (int k0 = 0; k0 < 1024; k0 += 16) {
#pragma unroll
        for (int l = 0; l < 4; l++) {
            int e = tid + l * 256;
            int oc = e >> 4, kk = e & 15;
            As[kk][oc] = w_pw[(long)(oc0 + oc) * 1024 + (k0 + kk)];
        }
#pragma unroll
        for (int l = 0; l < 12; l++) {
            int e = tid + l * 256;          // < 3072
            int n = e & 63, idx = e >> 6;   // idx = kk*3 + r
            int kk = idx / 3, r = idx - kk * 3;
            int row = y + r - 1;
            float v = (row >= 0 && row < 64)
                ? __bfloat162float(Qb[(long)(k0 + kk) * HW + row * 64 + n]) : 0.f;
            Xr[idx][n] = v;
        }
        __syncthreads();
#pragma unroll
        for (int l = 0; l < 4; l++) {
            int e = tid + l * 256;
            int kk = e >> 6, x = e & 63;
            int c = k0 + kk;
            float a = 0.f;
#pragma unroll
            for (int dy = 0; dy < 3; dy++)
#pragma unroll
                for (int dx = 0; dx < 3; dx++) {
                    int xx = x + dx - 1;
                    if (xx < 0 || xx >= 64) continue;
                    a = fmaf(w_dw[c * 9 + dy * 3 + dx], Xr[kk * 3 + dy][xx], a);
                }
            Bs[kk][x] = fmaxf(fmaf(s_dw[c], a, b_dw[c]), 0.f);
        }
        __syncthreads();
#pragma unroll
        for (int kk = 0; kk < 16; kk++) {
            float a[4], bv[4];
            *(float4*)a  = *(const float4*)&As[kk][ty * 4];
            *(float4*)bv = *(const float4*)&Bs[kk][tx * 4];
#pragma unroll
            for (int i = 0; i < 4; i++)
#pragma unroll
                for (int j = 0; j < 4; j++)
                    acc[i][j] = fmaf(a[i], bv[j], acc[i][j]);
        }
        __syncthreads();
    }
#pragma unroll
    for (int i = 0; i < 4; i++) {
        int oc = oc0 + ty * 4 + i;
#pragma unroll
        for (int j = 0; j < 4; j++) {
            int n = tx * 4 + j;
            out[(long)b * (256L * HW) + (long)oc * HW + y * 64 + n] = acc[i][j];
        }
    }
}

// ======================= vertical stripe conv (7x1) =======================
__global__ __launch_bounds__(256) void stripe_v(
    const float* __restrict__ in, long in_b, int IC,
    const float* __restrict__ w, int w_d, int w_o, int w_i,
    const float* __restrict__ cterm,
    float* __restrict__ out, long out_b, int OC, int accumulate)
{
    __shared__ __align__(16) float Ws[16][68];
    __shared__ __align__(16) float Xs[16][64];
    int b = blockIdx.z, y = blockIdx.y, oc0 = blockIdx.x * 64;
    int tid = threadIdx.x;
    int tx = tid & 15, ty = tid >> 4;
    float acc[4][4] = {};

    for (int d = 0; d < 7; d++) {
        int row = y + d - 3;
        if (row < 0 || row >= 64) continue;
        for (int k0 = 0; k0 < IC; k0 += 16) {
#pragma unroll
            for (int l = 0; l < 4; l++) {
                int e = tid + l * 256;
                int oc = e >> 4, kk = e & 15;
                Ws[kk][oc] = w[d * w_d + (oc0 + oc) * w_o + (k0 + kk) * w_i];
            }
#pragma unroll
            for (int l = 0; l < 4; l++) {
                int e = tid + l * 256;
                int kk = e >> 6, n = e & 63;
                Xs[kk][n] = in[(long)b * in_b + (long)(k0 + kk) * HW + row * 64 + n];
            }
            __syncthreads();
#pragma unroll
            for (int kk = 0; kk < 16; kk++) {
                float a[4], bv[4];
                *(float4*)a  = *(const float4*)&Ws[kk][ty * 4];
                *(float4*)bv = *(const float4*)&Xs[kk][tx * 4];
#pragma unroll
                for (int i = 0; i < 4; i++)
#pragma unroll
                    for (int j = 0; j < 4; j++)
                        acc[i][j] = fmaf(a[i], bv[j], acc[i][j]);
            }
            __syncthreads();
        }
    }

    float c4[4] = {0.f, 0.f, 0.f, 0.f};
    if (cterm) {
        for (int d = 0; d < 7; d++) {
            int row = y + d - 3;
            if (row < 0 || row >= 64) continue;
#pragma unroll
            for (int i = 0; i < 4; i++) c4[i] += cterm[d * OC + oc0 + ty * 4 + i];
        }
    }
#pragma unroll
    for (int i = 0; i < 4; i++) {
        int oc = oc0 + ty * 4 + i;
#pragma unroll
        for (int j = 0; j < 4; j++) {
            int n = tx * 4 + j;
            long oidx = (long)b * out_b + (long)oc * HW + y * 64 + n;
            float v = acc[i][j] + c4[i];
            if (accumulate) v += out[oidx];
            out[oidx] = v;
        }
    }
}

// ======================= horizontal stripe conv (1x7) =======================
__global__ __launch_bounds__(256) void stripe_h(
    const float* __restrict__ in, long in_b, int IC,
    const float* __restrict__ w, int w_d, int w_o, int w_i,
    const float* __restrict__ cterm,
    float* __restrict__ out, long out_b, int OC, int accumulate)
{
    __shared__ __align__(16) float Ws[16][68];
    __shared__ float Xs[16][72];   // 70 used (64 + 2*3 halo)
    int b = blockIdx.z, y = blockIdx.y, oc0 = blockIdx.x * 64;
    int tid = threadIdx.x;
    int tx = tid & 15, ty = tid >> 4;
    float acc[4][4] = {};

    for (int k0 = 0; k0 < IC; k0 += 16) {
        for (int e = tid; e < 16 * 70; e += 256) {
            int kk = e / 70, xx = e % 70;
            int x = xx - 3;
            float v = (x >= 0 && x < 64)
                ? in[(long)b * in_b + (long)(k0 + kk) * HW + y * 64 + x] : 0.f;
            Xs[kk][xx] = v;
        }
        for (int d = 0; d < 7; d++) {
#pragma unroll
            for (int l = 0; l < 4; l++) {
                int e = tid + l * 256;
                int oc = e >> 4, kk = e & 15;
                Ws[kk][oc] = w[d * w_d + (oc0 + oc) * w_o + (k0 + kk) * w_i];
            }
            __syncthreads();
#pragma unroll
            for (int kk = 0; kk < 16; kk++) {
                float a[4];
                *(float4*)a = *(const float4*)&Ws[kk][ty * 4];
#pragma unroll
                for (int j = 0; j < 4; j++) {
                    float xv = Xs[kk][tx * 4 + j + d];
#pragma unroll
                    for (int i = 0; i < 4; i++)
                        acc[i][j] = fmaf(a[i], xv, acc[i][j]);
                }
            }
            __syncthreads();
        }
    }

    float cij[4][4] = {};
    if (cterm) {
        for (int d = 0; d < 7; d++) {
#pragma unroll
            for (int j = 0; j < 4; j++) {
                int xs = tx * 4 + j + d - 3;
                if (xs < 0 || xs >= 64) continue;
#pragma unroll
                for (int i = 0; i < 4; i++)
                    cij[i][j] += cterm[d * OC + oc0 + ty * 4 + i];
            }
        }
    }
#pragma unroll
    for (int i = 0; i < 4; i++) {
        int oc = oc0 + ty * 4 + i;
#pragma unroll
        for (int j = 0; j < 4; j++) {
            int n = tx * 4 + j;
            long oidx = (long)b * out_b + (long)oc * HW + y * 64 + n;
            float v = acc[i][j] + cij[i][j];
            if (accumulate) v += out[oidx];
            out[oidx] = v;
        }
    }
}

// ======================= act_dn =======================
__global__ __launch_bounds__(256) void softmax_sp(float* __restrict__ x)
{
    __shared__ float red[4];
    float* p = x + (long)blockIdx.x * HW;
    int tid = threadIdx.x;
    float m = -1e30f;
    for (int i = tid; i < HW; i += 256) m = fmaxf(m, p[i]);
    for (int o = 32; o > 0; o >>= 1) m = fmaxf(m, __shfl_down(m, o));
    if ((tid & 63) == 0) red[tid >> 6] = m;
    __syncthreads();
    m = fmaxf(fmaxf(red[0], red[1]), fmaxf(red[2], red[3]));
    __syncthreads();
    float z = 0.f;
    for (int i = tid; i < HW; i += 256) z += __expf(p[i] - m);
    for (int o = 32; o > 0; o >>= 1) z += __shfl_down(z, o);
    if ((tid & 63) == 0) red[tid >> 6] = z;
    __syncthreads();
    z = red[0] + red[1] + red[2] + red[3];
    float inv = 1.f / z;
    for (int i = tid; i < HW; i += 256) p[i] = __expf(p[i] - m) * inv;
}

__global__ __launch_bounds__(256) void group_renorm(float* __restrict__ x)
{
    long t = (long)blockIdx.x * 256 + threadIdx.x;   // B*8*4096
    int s = (int)(t & 4095);
    int h = (int)((t >> 12) & 7);
    int b = (int)(t >> 15);
    float* base = x + (((long)(b * 64 + h * 8)) << 12) + s;
    float v[8]; float g = 0.f;
#pragma unroll
    for (int j = 0; j < 8; j++) { v[j] = base[(long)j << 12]; g += v[j]; }
    float inv = 1.f / (g + 1e-6f);
#pragma unroll
    for (int j = 0; j < 8; j++) base[(long)j << 12] = v[j] * inv;
}

// ======================= row/col means of qkv0 (bf16) =======================
__global__ __launch_bounds__(64) void meanrc(
    const bf16* __restrict__ in, float* __restrict__ rowm, float* __restrict__ colm)
{
    __shared__ float tile[64][65];
    int bc = blockIdx.x;                 // B*1024
    const bf16* p = in + (long)bc * HW;
    int t = threadIdx.x;
    for (int i = 0; i < 64; i++) tile[i][t] = __bfloat162float(p[i * 64 + t]);
    __syncthreads();
    float rs = 0.f, cs = 0.f;
    for (int i = 0; i < 64; i++) { rs += tile[t][i]; cs += tile[i][t]; }
    rowm[(long)bc * 64 + t] = rs * (1.f / 64.f);
    colm[(long)bc * 64 + t] = cs * (1.f / 64.f);
}

// ======================= squeeze attention =======================
__device__ __forceinline__ float interp_pe(const float* pe, int c, int i)
{
    float coord = fminf(fmaxf((i + 0.5f) * 0.25f - 0.5f, 0.f), 15.f);
    int lo = (int)coord;
    int hi = min(lo + 1, 15);
    float t = coord - (float)lo;
    return pe[c * 16 + lo] * (1.f - t) + pe[c * 16 + hi] * t;
}

__global__ __launch_bounds__(256) void attn_kernel(
    const float* __restrict__ rowm, const float* __restrict__ colm,
    const float* __restrict__ pe_rq, const float* __restrict__ pe_rk,
    const float* __restrict__ pe_cq, const float* __restrict__ pe_ck,
    float* __restrict__ outr, float* __restrict__ outc)
{
    int h = blockIdx.x, b = blockIdx.y, dir = blockIdx.z;
    const float* mean = dir ? colm : rowm;
    const float* peq = dir ? pe_cq : pe_rq;
    const float* pek = dir ? pe_ck : pe_rk;
    float* outp = (dir ? outc : outr) + ((long)b * 512 + h * 64) * 64;
    __shared__ float qs[32][64], ks[32][64], vs[64][64], S[64][66];
    int tid = threadIdx.x;

    for (int e = tid; e < 2048; e += 256) {
        int c = e >> 6, i = e & 63;
        int gc = h * 32 + c;
        qs[c][i] = mean[((long)b * 1024 + gc) * 64 + i]       + interp_pe(peq, gc, i);
        ks[c][i] = mean[((long)b * 1024 + 256 + gc) * 64 + i] + interp_pe(pek, gc, i);
    }
    for (int e = tid; e < 4096; e += 256) {
        int dc = e >> 6, j = e & 63;
        vs[dc][j] = mean[((long)b * 1024 + 512 + h * 64 + dc) * 64 + j];
    }
    __syncthreads();
    const float scl = 0.17677669529663687f;  // 32^-0.5
    for (int e = tid; e < 4096; e += 256) {
        int i = e >> 6, j = e & 63;
        float s = 0.f;
#pragma unroll
        for (int c = 0; c < 32; c++) s = fmaf(qs[c][i], ks[c][j], s);
        S[i][j] = s * scl;
    }
    __syncthreads();
    if (tid < 64) {
        int i = tid;
        float m = -1e30f;
        for (int j = 0; j < 64; j++) m = fmaxf(m, S[i][j]);
        float z = 0.f;
        for (int j = 0; j < 64; j++) { float e2 = __expf(S[i][j] - m); S[i][j] = e2; z += e2; }
        float inv = 1.f / z;
        for (int j = 0; j < 64; j++) S[i][j] *= inv;
    }
    __syncthreads();
    for (int e = tid; e < 4096; e += 256) {
        int dc = e >> 6, i = e & 63;
        float o = 0.f;
#pragma unroll
        for (int j = 0; j < 64; j++) o = fmaf(S[i][j], vs[dc][j], o);
        outp[dc * 64 + i] = o;
    }
}

// ======================= weight pre-contraction =======================
__global__ __launch_bounds__(256) void build_wga(
    const float* __restrict__ wq, const float* __restrict__ wk, const float* __restrict__ wv,
    const float* __restrict__ sq, const float* __restrict__ sk, const float* __restrict__ sv,
    const float* __restrict__ bq, const float* __restrict__ bk, const float* __restrict__ bv,
    const float* __restrict__ cov_s, const float* __restrict__ cov_b,
    float* __restrict__ Wga, float* __restrict__ beta)
{
    int idx = blockIdx.x * 256 + threadIdx.x;   // 1024*256
    int ic = idx >> 8, i = idx & 255;
    const float* Wp; float sth, bth;
    if (ic < 256)      { Wp = wq + ic * 256;         sth = sq[ic];       bth = bq[ic]; }
    else if (ic < 512) { Wp = wk + (ic - 256) * 256; sth = sk[ic - 256]; bth = bk[ic - 256]; }
    else               { Wp = wv + (ic - 512) * 256; sth = sv[ic - 512]; bth = bv[ic - 512]; }
    Wga[idx] = cov_s[ic] * sth * Wp[i];
    if (i == 0) beta[ic] = cov_s[ic] * bth + cov_b[ic];
}

__global__ __launch_bounds__(256) void build_N(
    const float* __restrict__ kvw, const float* __restrict__ Wga, float* __restrict__ N)
{
    int d = blockIdx.x >> 6, oc = blockIdx.x & 63;
    int i = threadIdx.x;
    float a = 0.f;
    for (int ic = 0; ic < 1024; ic++)
        a = fmaf(kvw[oc * 7168 + ic * 7 + d], Wga[ic * 256 + i], a);
    N[(long)blockIdx.x * 256 + i] = a;
}

__global__ __launch_bounds__(64) void build_C(
    const float* __restrict__ kvw, const float* __restrict__ beta, float* __restrict__ C)
{
    int d = blockIdx.x, oc = threadIdx.x;
    float a = 0.f;
    for (int ic = 0; ic < 1024; ic++)
        a = fmaf(kvw[oc * 7168 + ic * 7 + d], beta[ic], a);
    C[d * 64 + oc] = a;
}

__global__ __launch_bounds__(64) void build_M(
    const float* __restrict__ wpw, const float* __restrict__ kvw, float* __restrict__ M)
{
    int d = blockIdx.x >> 8, o = blockIdx.x & 255;
    int ic = threadIdx.x;
    float a = 0.f;
    for (int c2 = 0; c2 < 1024; c2++)
        a = fmaf(wpw[o * 1024 + c2], kvw[ic * 7168 + c2 * 7 + d], a);
    M[(long)blockIdx.x * 64 + ic] = a;
}

// ======================= launch =======================
extern "C" void kernel_launch(void* const* d_in, const int* in_sizes, int n_in,
                              void* d_out, int out_size, void* d_ws, size_t ws_size,
                              hipStream_t stream)
{
    const float* x     = (const float*)d_in[0];
    const float* wq    = (const float*)d_in[1];
    const float* sq    = (const float*)d_in[2];
    const float* bq    = (const float*)d_in[3];
    const float* wk    = (const float*)d_in[4];
    const float* sk    = (const float*)d_in[5];
    const float* bk    = (const float*)d_in[6];
    const float* wv    = (const float*)d_in[7];
    const float* sv    = (const float*)d_in[8];
    const float* bv    = (const float*)d_in[9];
    const float* w_dw  = (const float*)d_in[10];
    const float* s_dw  = (const float*)d_in[11];
    const float* b_dw  = (const float*)d_in[12];
    const float* cov_s = (const float*)d_in[13];
    const float* cov_b = (const float*)d_in[14];
    const float* kv    = (const float*)d_in[15];
    const float* kv3   = (const float*)d_in[16];
    const float* w_pw  = (const float*)d_in[17];
    const float* s_pw  = (const float*)d_in[18];
    const float* b_pw  = (const float*)d_in[19];
    const float* w_row = (const float*)d_in[20];
    const float* s_row = (const float*)d_in[21];
    const float* b_row = (const float*)d_in[22];
    const float* w_col = (const float*)d_in[23];
    const float* s_col = (const float*)d_in[24];
    const float* b_col = (const float*)d_in[25];
    const float* w_proj= (const float*)d_in[26];
    const float* s_proj= (const float*)d_in[27];
    const float* b_proj= (const float*)d_in[28];
    const float* pe_rq = (const float*)d_in[29];
    const float* pe_rk = (const float*)d_in[30];
    const float* pe_cq = (const float*)d_in[31];
    const float* pe_ck = (const float*)d_in[32];
    float* out = (float*)d_out;

    // ---- workspace layout (bytes). total ~122.5 MB ----
    char* wsb = (char*)d_ws;
    size_t off = 0;
    auto alloc = [&](size_t bytes) { char* p = wsb + off; off += (bytes + 255) & ~255UL; return p; };
    bf16*  qkv0  = (bf16*) alloc(33554432L * 2);   // (8,1024,4096) bf16
    float* qkvpw = (float*)alloc(8388608L * 4);    // (8,256,4096) fp32 raw
    float* outr  = (float*)alloc(262144L * 4);     // (8,512,64)
    float* outc  = (float*)alloc(262144L * 4);
    float* Wga   = (float*)alloc(262144L * 4);     // (1024,256)
    float* beta  = (float*)alloc(1024L * 4);
    float* Nv    = (float*)alloc(114688L * 4);     // (7,64,256)
    float* Nh    = (float*)alloc(114688L * 4);
    float* Cv    = (float*)alloc(448L * 4);
    float* Ch    = (float*)alloc(448L * 4);
    float* Mv    = (float*)alloc(114688L * 4);     // (7,256,64)
    float* Mh    = (float*)alloc(114688L * 4);
    char*  ovl   = alloc(16777216);                // overlay region, 16 MB
    // overlay layout 1 (attention phase): rowm, colm, atr, atc
    float* rowm = (float*)ovl;                     // (8,1024,64)  2 MB
    float* colm = (float*)(ovl + 2097152);         //              2 MB
    float* atr  = (float*)(ovl + 4194304);         // (8,512,64)   1 MB
    float* atc  = (float*)(ovl + 5242880);         //              1 MB
    // overlay layout 2 (stripe phase): x1a, x3a
    float* x1a  = (float*)ovl;                     // (8,64,4096)  8 MB
    float* x3a  = (float*)(ovl + 8388608);         //              8 MB
    if (off > ws_size) return;  // insufficient workspace -> clean fail (absmax = max|ref|)

    const long XB = 256L * 4096;   // x batch stride (elems)
    const long QB = 1024L * 4096;  // qkv0 batch stride (elems)
    const long PB = 256L * 4096;
    const long AB = 512L * 64;

    // ---- weight pre-contraction ----
    build_wga<<<1024, 256, 0, stream>>>(wq, wk, wv, sq, sk, sv, bq, bk, bv, cov_s, cov_b, Wga, beta);
    build_N<<<448, 256, 0, stream>>>(kv,  Wga, Nv);
    build_N<<<448, 256, 0, stream>>>(kv3, Wga, Nh);
    build_C<<<7, 64, 0, stream>>>(kv,  beta, Cv);
    build_C<<<7, 64, 0, stream>>>(kv3, beta, Ch);
    build_M<<<1792, 64, 0, stream>>>(w_pw, kv,  Mv);
    build_M<<<1792, 64, 0, stream>>>(w_pw, kv3, Mh);

    // ---- qkv0 = bn(1x1 conv), stored bf16 ----
    gemm1x1<<<dim3(64, 4, 8), 256, 0, stream>>>(x, XB, 0, wq, sq, bq, qkv0,              QB, 1, 256, 256, 4096, 0, nullptr, nullptr, 0, 0, nullptr, 0, nullptr, nullptr);
    gemm1x1<<<dim3(64, 4, 8), 256, 0, stream>>>(x, XB, 0, wk, sk, bk, qkv0 + 256 * 4096, QB, 1, 256, 256, 4096, 0, nullptr, nullptr, 0, 0, nullptr, 0, nullptr, nullptr);
    gemm1x1<<<dim3(64, 8, 8), 256, 0, stream>>>(x, XB, 0, wv, sv, bv, qkv0 + 512 * 4096, QB, 1, 512, 256, 4096, 0, nullptr, nullptr, 0, 0, nullptr, 0, nullptr, nullptr);

    // ---- squeeze attention (uses overlay layout 1; must finish before stripes) ----
    meanrc<<<8192, 64, 0, stream>>>(qkv0, rowm, colm);
    attn_kernel<<<dim3(8, 8, 2), 256, 0, stream>>>(rowm, colm, pe_rq, pe_rk, pe_cq, pe_ck, atr, atc);
    gemm1x1<<<dim3(1, 8, 8), 256, 0, stream>>>(atr, AB, 0, w_row, s_row, b_row, outr, AB, 0, 512, 512, 64, 1, nullptr, nullptr, 0, 0, nullptr, 0, nullptr, nullptr);
    gemm1x1<<<dim3(1, 8, 8), 256, 0, stream>>>(atc, AB, 0, w_col, s_col, b_col, outc, AB, 0, 512, 512, 64, 1, nullptr, nullptr, 0, 0, nullptr, 0, nullptr, nullptr);

    // ---- stripe conv 1 (fused bn+qkv conv), act_dn (overlay layout 2) ----
    stripe_v<<<dim3(1, 64, 8), 256, 0, stream>>>(x, XB, 256, Nv, 16384, 256, 1, Cv, x1a, 64L * 4096, 64, 0);
    softmax_sp<<<512, 256, 0, stream>>>(x1a);
    group_renorm<<<1024, 256, 0, stream>>>(x1a);
    stripe_h<<<dim3(1, 64, 8), 256, 0, stream>>>(x, XB, 256, Nh, 16384, 256, 1, Ch, x3a, 64L * 4096, 64, 0);
    softmax_sp<<<512, 256, 0, stream>>>(x3a);
    group_renorm<<<1024, 256, 0, stream>>>(x3a);

    // ---- pw conv base with fused dw3x3 (bn deferred) + stripe conv 2 via w_pw ----
    pw_dw_gemm<<<dim3(64, 4, 8), 256, 0, stream>>>(qkv0, w_pw, w_dw, s_dw, b_dw, qkvpw);
    stripe_v<<<dim3(4, 64, 8), 256, 0, stream>>>(x1a, 64L * 4096, 64, Mv, 16384, 64, 1, nullptr, qkvpw, PB, 256, 1);
    stripe_h<<<dim3(4, 64, 8), 256, 0, stream>>>(x3a, 64L * 4096, 64, Mh, 16384, 64, 1, nullptr, qkvpw, PB, 256, 1);

    // ---- final: proj on relu(v + out_r + out_c); sigmoid(.) * bn_pw(qkvpw) ----
    gemm1x1<<<dim3(64, 4, 8), 256, 0, stream>>>(qkv0 + 512 * 4096, QB, 1, w_proj, s_proj, b_proj,
                                                out, PB, 0, 256, 512, 4096, 1,
                                                outr, outc, AB,
                                                1, qkvpw, PB, s_pw, b_pw);
}

// Round 3
// 1368.505 us; speedup vs baseline: 2.7921x; 2.7921x over previous
//
#include <hip/hip_runtime.h>
#include <hip/hip_bf16.h>
#include <math.h>

#define HW 4096
typedef __hip_bfloat16 bf16;
typedef __attribute__((ext_vector_type(8))) short bfrag;
typedef __attribute__((ext_vector_type(4))) float ffrag;

__device__ __forceinline__ float bf2f(short u) {
    return __uint_as_float(((unsigned)(unsigned short)u) << 16);
}
__device__ __forceinline__ short f2bfs(float v) {
    bf16 h = __float2bfloat16(v);
    return *reinterpret_cast<short*>(&h);
}

// ======================= cast + transpose x: [256][4096] -> [4096][256] bf16 ==========
__global__ __launch_bounds__(256) void cast_xt(const float* __restrict__ x, bf16* __restrict__ xt)
{
    __shared__ float t[64][65];
    int b = blockIdx.z, it = blockIdx.y, pt = blockIdx.x;
    int ic0 = it * 64, px0 = pt * 64;
    int tid = threadIdx.x;
    for (int l = 0; l < 16; l++) {
        int e = tid + l * 256;
        int px = e & 63, ic = e >> 6;
        t[ic][px] = x[((long)b * 256 + ic0 + ic) * HW + px0 + px];
    }
    __syncthreads();
    for (int l = 0; l < 16; l++) {
        int e = tid + l * 256;
        int ic = e & 63, px = e >> 6;
        xt[((long)b * HW + px0 + px) * 256 + ic0 + ic] = __float2bfloat16(t[ic][px]);
    }
}

// ======================= weight casts ==========
__global__ __launch_bounds__(256) void castw(
    const float* __restrict__ wq, const float* __restrict__ wk, const float* __restrict__ wv,
    const float* __restrict__ sq, const float* __restrict__ sk, const float* __restrict__ sv,
    const float* __restrict__ bq, const float* __restrict__ bk, const float* __restrict__ bv,
    const float* __restrict__ w_pw, const float* __restrict__ w_proj,
    bf16* __restrict__ Wall, bf16* __restrict__ wpw_bf, bf16* __restrict__ wproj_bf,
    float* __restrict__ sb_s, float* __restrict__ sb_b)
{
    int idx = blockIdx.x * 256 + threadIdx.x;
    if (idx < 262144) {
        int oc = idx >> 8, i = idx & 255;
        float v;
        if (oc < 256) v = wq[oc * 256 + i];
        else if (oc < 512) v = wk[(oc - 256) * 256 + i];
        else v = wv[(oc - 512) * 256 + i];
        Wall[idx] = __float2bfloat16(v);
        return;
    }
    idx -= 262144;
    if (idx < 262144) { wpw_bf[idx] = __float2bfloat16(w_pw[idx]); return; }
    idx -= 262144;
    if (idx < 131072) { wproj_bf[idx] = __float2bfloat16(w_proj[idx]); return; }
    idx -= 131072;
    if (idx < 1024) {
        int oc = idx;
        float s, bb;
        if (oc < 256) { s = sq[oc]; bb = bq[oc]; }
        else if (oc < 512) { s = sk[oc - 256]; bb = bk[oc - 256]; }
        else { s = sv[oc - 512]; bb = bv[oc - 512]; }
        sb_s[oc] = s; sb_b[oc] = bb;
    }
}

// ======================= MFMA qkv GEMM: qkv0[b][1024][4096] = bn(Wall x) ==========
__global__ __launch_bounds__(256) void mfma_qkv(
    const bf16* __restrict__ Xt, const bf16* __restrict__ Wall,
    const float* __restrict__ sb_s, const float* __restrict__ sb_b,
    bf16* __restrict__ qkv0)
{
    __shared__ __align__(16) short As[128 * 40];
    __shared__ __align__(16) short Bs[128 * 40];
    int b = blockIdx.z, mt = blockIdx.y, nt = blockIdx.x;
    int oc0 = mt * 128, n0 = nt * 128;
    int tid = threadIdx.x;
    int lane = tid & 63, wave = tid >> 6;
    int lr = lane & 15, quad = lane >> 4;
    int wm = (wave & 1) * 64, wn = (wave >> 1) * 64;
    ffrag acc[4][4];
#pragma unroll
    for (int i = 0; i < 4; i++)
#pragma unroll
        for (int j = 0; j < 4; j++)
#pragma unroll
            for (int r = 0; r < 4; r++) acc[i][j][r] = 0.f;

    for (int k0 = 0; k0 < 256; k0 += 32) {
#pragma unroll
        for (int l = 0; l < 2; l++) {
            int e = tid + l * 256;
            int r = e >> 2, c = e & 3;
            *(int4*)&As[r * 40 + c * 8] = *(const int4*)&Wall[(long)(oc0 + r) * 256 + k0 + c * 8];
            *(int4*)&Bs[r * 40 + c * 8] = *(const int4*)&Xt[((long)b * HW + n0 + r) * 256 + k0 + c * 8];
        }
        __syncthreads();
        bfrag a[4], bb[4];
#pragma unroll
        for (int i = 0; i < 4; i++) a[i]  = *(const bfrag*)&As[(wm + i * 16 + lr) * 40 + quad * 8];
#pragma unroll
        for (int j = 0; j < 4; j++) bb[j] = *(const bfrag*)&Bs[(wn + j * 16 + lr) * 40 + quad * 8];
#pragma unroll
        for (int i = 0; i < 4; i++)
#pragma unroll
            for (int j = 0; j < 4; j++)
                acc[i][j] = __builtin_amdgcn_mfma_f32_16x16x32_bf16(a[i], bb[j], acc[i][j], 0, 0, 0);
        __syncthreads();
    }
#pragma unroll
    for (int i = 0; i < 4; i++)
#pragma unroll
        for (int r = 0; r < 4; r++) {
            int row = oc0 + wm + i * 16 + quad * 4 + r;
            float s = sb_s[row], bb2 = sb_b[row];
#pragma unroll
            for (int j = 0; j < 4; j++) {
                int col = n0 + wn + j * 16 + lr;
                qkv0[((long)b * 1024 + row) * HW + col] = __float2bfloat16(fmaf(s, acc[i][j][r], bb2));
            }
        }
}

// ======================= MFMA pw GEMM with fused dw3x3+bn+relu B ==========
// qkvpw[b][256][4096] (bf16, raw pre-bn) = w_pw x relu(bn_dw(dw3x3(qkv0)))
__global__ __launch_bounds__(256) void mfma_pw_dw(
    const bf16* __restrict__ qkv0, const bf16* __restrict__ wpw_bf,
    const float* __restrict__ w_dw, const float* __restrict__ s_dw, const float* __restrict__ b_dw,
    bf16* __restrict__ qkvpw)
{
    __shared__ __align__(16) short As[128 * 40];
    __shared__ __align__(16) short Bst[32 * 136];
    int b = blockIdx.z, mt = blockIdx.y, nt = blockIdx.x;
    int oc0 = mt * 128, y0 = nt * 2, px0 = nt * 128;
    int tid = threadIdx.x;
    int lane = tid & 63, wave = tid >> 6;
    int lr = lane & 15, quad = lane >> 4;
    int wm = (wave & 1) * 64, wn = (wave >> 1) * 64;
    // dw unit: thread handles 16 px x 1 channel
    int dc = tid >> 3;            // 0..31 channel within slab
    int ux = tid & 7;             // 0..7 -> px = ux*16..+16
    int drow = ux >> 2;           // output row 0/1
    int xb = (ux & 3) * 16;       // x base
    ffrag acc[4][4];
#pragma unroll
    for (int i = 0; i < 4; i++)
#pragma unroll
        for (int j = 0; j < 4; j++)
#pragma unroll
            for (int r = 0; r < 4; r++) acc[i][j][r] = 0.f;

    for (int k0 = 0; k0 < 1024; k0 += 32) {
#pragma unroll
        for (int l = 0; l < 2; l++) {
            int e = tid + l * 256;
            int r = e >> 2, c = e & 3;
            *(int4*)&As[r * 40 + c * 8] = *(const int4*)&wpw_bf[(long)(oc0 + r) * 1024 + k0 + c * 8];
        }
        // ---- fused dw3x3 for this 32-ch slab ----
        {
            int ch = k0 + dc;
            float wd[9];
#pragma unroll
            for (int t = 0; t < 9; t++) wd[t] = w_dw[ch * 9 + t];
            float o16[16];
#pragma unroll
            for (int t = 0; t < 16; t++) o16[t] = 0.f;
            const bf16* base = qkv0 + ((long)b * 1024 + ch) * HW;
#pragma unroll
            for (int dy = 0; dy < 3; dy++) {
                int gr = y0 + drow + dy - 1;
                float w[18];
                if (gr >= 0 && gr < 64) {
                    short ck[4][8];
#pragma unroll
                    for (int c4 = 0; c4 < 4; c4++) {
                        int xcol = xb - 8 + c4 * 8;
                        if (xcol >= 0 && xcol <= 56)
                            *(int4*)ck[c4] = *(const int4*)&base[gr * 64 + xcol];
                        else {
                            int4 z = {0, 0, 0, 0};
                            *(int4*)ck[c4] = z;
                        }
                    }
#pragma unroll
                    for (int t = 0; t < 18; t++)
                        w[t] = bf2f(ck[(t + 7) >> 3][(t + 7) & 7]);
                } else {
#pragma unroll
                    for (int t = 0; t < 18; t++) w[t] = 0.f;
                }
#pragma unroll
                for (int dx = 0; dx < 3; dx++) {
                    float wt = wd[dy * 3 + dx];
#pragma unroll
                    for (int o = 0; o < 16; o++)
                        o16[o] = fmaf(wt, w[o + dx], o16[o]);
                }
            }
            float ss = s_dw[ch], bb0 = b_dw[ch];
            short pk[16];
#pragma unroll
            for (int o = 0; o < 16; o++)
                pk[o] = f2bfs(fmaxf(fmaf(ss, o16[o], bb0), 0.f));
            *(int4*)&Bst[dc * 136 + ux * 16]     = *(int4*)&pk[0];
            *(int4*)&Bst[dc * 136 + ux * 16 + 8] = *(int4*)&pk[8];
        }
        __syncthreads();
        bfrag a[4], bb[4];
#pragma unroll
        for (int i = 0; i < 4; i++) a[i] = *(const bfrag*)&As[(wm + i * 16 + lr) * 40 + quad * 8];
#pragma unroll
        for (int j = 0; j < 4; j++) {
            int col = wn + j * 16 + lr;
#pragma unroll
            for (int e = 0; e < 8; e++) bb[j][e] = Bst[(quad * 8 + e) * 136 + col];
        }
#pragma unroll
        for (int i = 0; i < 4; i++)
#pragma unroll
            for (int j = 0; j < 4; j++)
                acc[i][j] = __builtin_amdgcn_mfma_f32_16x16x32_bf16(a[i], bb[j], acc[i][j], 0, 0, 0);
        __syncthreads();
    }
#pragma unroll
    for (int i = 0; i < 4; i++)
#pragma unroll
        for (int r = 0; r < 4; r++) {
            int row = oc0 + wm + i * 16 + quad * 4 + r;
#pragma unroll
            for (int j = 0; j < 4; j++) {
                int col = px0 + wn + j * 16 + lr;
                qkvpw[((long)b * 256 + row) * HW + col] = __float2bfloat16(acc[i][j][r]);
            }
        }
}

// ======================= MFMA proj GEMM with fused epilogue ==========
// out[b][256][4096] = (s_pw*qkvpw+b_pw) * sigmoid(s_proj*(W_proj x relu(v+outr+outc))+b_proj)
__global__ __launch_bounds__(256) void mfma_proj(
    const bf16* __restrict__ qkv0, const bf16* __restrict__ wproj_bf,
    const float* __restrict__ outr, const float* __restrict__ outc,
    const float* __restrict__ s_proj, const float* __restrict__ b_proj,
    const bf16* __restrict__ qkvpw, const float* __restrict__ s_pw, const float* __restrict__ b_pw,
    float* __restrict__ out)
{
    __shared__ __align__(16) short As[128 * 40];
    __shared__ __align__(16) short Bst[32 * 136];
    int b = blockIdx.z, mt = blockIdx.y, nt = blockIdx.x;
    int oc0 = mt * 128, y0 = nt * 2, px0 = nt * 128;
    int tid = threadIdx.x;
    int lane = tid & 63, wave = tid >> 6;
    int lr = lane & 15, quad = lane >> 4;
    int wm = (wave & 1) * 64, wn = (wave >> 1) * 64;
    ffrag acc[4][4];
#pragma unroll
    for (int i = 0; i < 4; i++)
#pragma unroll
        for (int j = 0; j < 4; j++)
#pragma unroll
            for (int r = 0; r < 4; r++) acc[i][j][r] = 0.f;

    for (int k0 = 0; k0 < 512; k0 += 32) {
#pragma unroll
        for (int l = 0; l < 2; l++) {
            int e = tid + l * 256;
            int r = e >> 2, c = e & 3;
            *(int4*)&As[r * 40 + c * 8] = *(const int4*)&wproj_bf[(long)(oc0 + r) * 512 + k0 + c * 8];
        }
#pragma unroll
        for (int l = 0; l < 2; l++) {
            int e = tid + l * 256;
            int cx = e & 15, c = e >> 4;
            int dh = k0 + c;
            short v8[8];
            *(int4*)v8 = *(const int4*)&qkv0[((long)b * 1024 + 512 + dh) * HW + px0 + cx * 8];
            int yy = y0 + (cx >> 3);
            float ro = outr[((long)b * 512 + dh) * 64 + yy];
            const float* cbase = &outc[((long)b * 512 + dh) * 64];
            short pk[8];
#pragma unroll
            for (int p = 0; p < 8; p++) {
                int pxl = cx * 8 + p;
                float val = bf2f(v8[p]) + ro + cbase[pxl & 63];
                pk[p] = f2bfs(fmaxf(val, 0.f));
            }
            *(int4*)&Bst[c * 136 + cx * 8] = *(int4*)pk;
        }
        __syncthreads();
        bfrag a[4], bb[4];
#pragma unroll
        for (int i = 0; i < 4; i++) a[i] = *(const bfrag*)&As[(wm + i * 16 + lr) * 40 + quad * 8];
#pragma unroll
        for (int j = 0; j < 4; j++) {
            int col = wn + j * 16 + lr;
#pragma unroll
            for (int e = 0; e < 8; e++) bb[j][e] = Bst[(quad * 8 + e) * 136 + col];
        }
#pragma unroll
        for (int i = 0; i < 4; i++)
#pragma unroll
            for (int j = 0; j < 4; j++)
                acc[i][j] = __builtin_amdgcn_mfma_f32_16x16x32_bf16(a[i], bb[j], acc[i][j], 0, 0, 0);
        __syncthreads();
    }
#pragma unroll
    for (int i = 0; i < 4; i++)
#pragma unroll
        for (int r = 0; r < 4; r++) {
            int row = oc0 + wm + i * 16 + quad * 4 + r;
            float sp = s_proj[row], bp = b_proj[row];
            float sw = s_pw[row], bw = b_pw[row];
#pragma unroll
            for (int j = 0; j < 4; j++) {
                int col = px0 + wn + j * 16 + lr;
                long idx = ((long)b * 256 + row) * HW + col;
                float t = fmaf(sp, acc[i][j][r], bp);
                float m = fmaf(sw, bf2f(*(const short*)&qkvpw[idx]), bw);
                out[idx] = m / (1.f + __expf(-t));
            }
        }
}

// ======================= MFMA stripe conv 1 (fused qkv+bn pre-contraction) ==========
// out[b][64][4096] bf16 = Nt(d) * x_t rows (+ cterm);  dir 0: vertical 7x1, dir 1: horizontal 1x7
__global__ __launch_bounds__(64) void mstripe1(
    const bf16* __restrict__ xt, const bf16* __restrict__ Nt, const float* __restrict__ C,
    bf16* __restrict__ outp, int dir)
{
    __shared__ __align__(16) short As[64 * 40];
    __shared__ __align__(16) short Bs[64 * 40];
    int y = blockIdx.x, b = blockIdx.y;
    int lane = threadIdx.x;
    int lr = lane & 15, quad = lane >> 4;
    ffrag acc[4][4];
#pragma unroll
    for (int i = 0; i < 4; i++)
#pragma unroll
        for (int j = 0; j < 4; j++)
#pragma unroll
            for (int r = 0; r < 4; r++) acc[i][j][r] = 0.f;

    for (int d = 0; d < 7; d++) {
        int off = d - 3;
        int row = y + off;
        if (dir == 0 && (row < 0 || row >= 64)) continue;
        for (int ks = 0; ks < 8; ks++) {
#pragma unroll
            for (int l = 0; l < 4; l++) {
                int e = lane + l * 64;
                int r = e >> 2, cc = e & 3;
                *(int4*)&As[r * 40 + cc * 8] = *(const int4*)&Nt[(long)r * 1792 + d * 256 + ks * 32 + cc * 8];
            }
#pragma unroll
            for (int l = 0; l < 4; l++) {
                int x = lane, cc = l;
                int4 v;
                if (dir == 0) {
                    v = *(const int4*)&xt[((long)b * HW + row * 64 + x) * 256 + ks * 32 + cc * 8];
                } else {
                    int xs = x + off;
                    if (xs >= 0 && xs < 64)
                        v = *(const int4*)&xt[((long)b * HW + y * 64 + xs) * 256 + ks * 32 + cc * 8];
                    else { int4 z = {0,0,0,0}; v = z; }
                }
                *(int4*)&Bs[x * 40 + cc * 8] = v;
            }
            __syncthreads();
            bfrag a[4], bb[4];
#pragma unroll
            for (int i = 0; i < 4; i++) a[i]  = *(const bfrag*)&As[(i * 16 + lr) * 40 + quad * 8];
#pragma unroll
            for (int j = 0; j < 4; j++) bb[j] = *(const bfrag*)&Bs[(j * 16 + lr) * 40 + quad * 8];
#pragma unroll
            for (int i = 0; i < 4; i++)
#pragma unroll
                for (int j = 0; j < 4; j++)
                    acc[i][j] = __builtin_amdgcn_mfma_f32_16x16x32_bf16(a[i], bb[j], acc[i][j], 0, 0, 0);
            __syncthreads();
        }
    }
#pragma unroll
    for (int i = 0; i < 4; i++)
#pragma unroll
        for (int r = 0; r < 4; r++) {
            int oc = i * 16 + quad * 4 + r;
#pragma unroll
            for (int j = 0; j < 4; j++) {
                int x = j * 16 + lr;
                float ct = 0.f;
                int base = dir ? x : y;
                for (int d = 0; d < 7; d++) {
                    int t = base + d - 3;
                    if (t >= 0 && t < 64) ct += C[d * 64 + oc];
                }
                outp[((long)b * 64 + oc) * HW + y * 64 + x] = __float2bfloat16(acc[i][j][r] + ct);
            }
        }
}

// ======================= MFMA stripe conv 2 (through w_pw), accumulate into qkvpw ==========
__global__ __launch_bounds__(256) void mstripe2(
    const bf16* __restrict__ inp, const bf16* __restrict__ Mt,
    bf16* __restrict__ qkvpw, int dir)
{
    __shared__ __align__(16) short As[128 * 40];
    __shared__ __align__(16) short Bst[32 * 136];
    int b = blockIdx.z, mt = blockIdx.y, nt = blockIdx.x;
    int oc0 = mt * 128, y0 = nt * 2, px0 = nt * 128;
    int tid = threadIdx.x;
    int lane = tid & 63, wave = tid >> 6;
    int lr = lane & 15, quad = lane >> 4;
    int wm = (wave & 1) * 64, wn = (wave >> 1) * 64;
    ffrag acc[4][4];
#pragma unroll
    for (int i = 0; i < 4; i++)
#pragma unroll
        for (int j = 0; j < 4; j++)
#pragma unroll
            for (int r = 0; r < 4; r++) acc[i][j][r] = 0.f;

    for (int d = 0; d < 7; d++) {
        int off = d - 3;
        for (int ks = 0; ks < 2; ks++) {
#pragma unroll
            for (int l = 0; l < 2; l++) {
                int e = tid + l * 256;
                int r = e >> 2, cc = e & 3;
                *(int4*)&As[r * 40 + cc * 8] = *(const int4*)&Mt[(long)(oc0 + r) * 448 + d * 64 + ks * 32 + cc * 8];
            }
#pragma unroll
            for (int l = 0; l < 2; l++) {
                int e = tid + l * 256;
                int cx = e & 15, c = e >> 4;
                int ic = ks * 32 + c;
                int rloc = cx >> 3;
                const bf16* src = &inp[((long)b * 64 + ic) * HW];
                if (dir == 0) {
                    int srow = y0 + rloc + off;
                    int4 v;
                    if (srow >= 0 && srow < 64)
                        v = *(const int4*)&src[srow * 64 + (cx & 7) * 8];
                    else { int4 z = {0,0,0,0}; v = z; }
                    *(int4*)&Bst[c * 136 + cx * 8] = v;
                } else {
                    short pk[8];
#pragma unroll
                    for (int p = 0; p < 8; p++) {
                        int xl = (cx & 7) * 8 + p;
                        int xs = xl + off;
                        pk[p] = (xs >= 0 && xs < 64) ? *(const short*)&src[(y0 + rloc) * 64 + xs] : (short)0;
                    }
                    *(int4*)&Bst[c * 136 + cx * 8] = *(int4*)pk;
                }
            }
            __syncthreads();
            bfrag a[4], bb[4];
#pragma unroll
            for (int i = 0; i < 4; i++) a[i] = *(const bfrag*)&As[(wm + i * 16 + lr) * 40 + quad * 8];
#pragma unroll
            for (int j = 0; j < 4; j++) {
                int col = wn + j * 16 + lr;
#pragma unroll
                for (int e = 0; e < 8; e++) bb[j][e] = Bst[(quad * 8 + e) * 136 + col];
            }
#pragma unroll
            for (int i = 0; i < 4; i++)
#pragma unroll
                for (int j = 0; j < 4; j++)
                    acc[i][j] = __builtin_amdgcn_mfma_f32_16x16x32_bf16(a[i], bb[j], acc[i][j], 0, 0, 0);
            __syncthreads();
        }
    }
#pragma unroll
    for (int i = 0; i < 4; i++)
#pragma unroll
        for (int r = 0; r < 4; r++) {
            int row = oc0 + wm + i * 16 + quad * 4 + r;
#pragma unroll
            for (int j = 0; j < 4; j++) {
                int col = px0 + wn + j * 16 + lr;
                long idx = ((long)b * 256 + row) * HW + col;
                float v = bf2f(*(const short*)&qkvpw[idx]) + acc[i][j][r];
                qkvpw[idx] = __float2bfloat16(v);
            }
        }
}

// ======================= act_dn (bf16) =======================
__global__ __launch_bounds__(256) void softmax_sp_bf(bf16* __restrict__ x)
{
    __shared__ float red[4];
    bf16* p = x + (long)blockIdx.x * HW;
    int tid = threadIdx.x;
    float m = -1e30f;
    for (int i = tid; i < HW; i += 256) m = fmaxf(m, __bfloat162float(p[i]));
    for (int o = 32; o > 0; o >>= 1) m = fmaxf(m, __shfl_down(m, o));
    if ((tid & 63) == 0) red[tid >> 6] = m;
    __syncthreads();
    m = fmaxf(fmaxf(red[0], red[1]), fmaxf(red[2], red[3]));
    __syncthreads();
    float z = 0.f;
    for (int i = tid; i < HW; i += 256) z += __expf(__bfloat162float(p[i]) - m);
    for (int o = 32; o > 0; o >>= 1) z += __shfl_down(z, o);
    if ((tid & 63) == 0) red[tid >> 6] = z;
    __syncthreads();
    z = red[0] + red[1] + red[2] + red[3];
    float inv = 1.f / z;
    for (int i = tid; i < HW; i += 256)
        p[i] = __float2bfloat16(__expf(__bfloat162float(p[i]) - m) * inv);
}

__global__ __launch_bounds__(256) void group_renorm_bf(bf16* __restrict__ x)
{
    long t = (long)blockIdx.x * 256 + threadIdx.x;   // B*8*4096
    int s = (int)(t & 4095);
    int h = (int)((t >> 12) & 7);
    int b = (int)(t >> 15);
    bf16* base = x + (((long)(b * 64 + h * 8)) << 12) + s;
    float v[8]; float g = 0.f;
#pragma unroll
    for (int j = 0; j < 8; j++) { v[j] = __bfloat162float(base[(long)j << 12]); g += v[j]; }
    float inv = 1.f / (g + 1e-6f);
#pragma unroll
    for (int j = 0; j < 8; j++) base[(long)j << 12] = __float2bfloat16(v[j] * inv);
}

// ======================= row/col means of qkv0 (bf16) =======================
__global__ __launch_bounds__(64) void meanrc(
    const bf16* __restrict__ in, float* __restrict__ rowm, float* __restrict__ colm)
{
    __shared__ float tile[64][65];
    int bc = blockIdx.x;
    const bf16* p = in + (long)bc * HW;
    int t = threadIdx.x;
    for (int i = 0; i < 64; i++) tile[i][t] = __bfloat162float(p[i * 64 + t]);
    __syncthreads();
    float rs = 0.f, cs = 0.f;
    for (int i = 0; i < 64; i++) { rs += tile[t][i]; cs += tile[i][t]; }
    rowm[(long)bc * 64 + t] = rs * (1.f / 64.f);
    colm[(long)bc * 64 + t] = cs * (1.f / 64.f);
}

// ======================= squeeze attention =======================
__device__ __forceinline__ float interp_pe(const float* pe, int c, int i)
{
    float coord = fminf(fmaxf((i + 0.5f) * 0.25f - 0.5f, 0.f), 15.f);
    int lo = (int)coord;
    int hi = min(lo + 1, 15);
    float t = coord - (float)lo;
    return pe[c * 16 + lo] * (1.f - t) + pe[c * 16 + hi] * t;
}

__global__ __launch_bounds__(256) void attn_kernel(
    const float* __restrict__ rowm, const float* __restrict__ colm,
    const float* __restrict__ pe_rq, const float* __restrict__ pe_rk,
    const float* __restrict__ pe_cq, const float* __restrict__ pe_ck,
    float* __restrict__ outr, float* __restrict__ outc)
{
    int h = blockIdx.x, b = blockIdx.y, dir = blockIdx.z;
    const float* mean = dir ? colm : rowm;
    const float* peq = dir ? pe_cq : pe_rq;
    const float* pek = dir ? pe_ck : pe_rk;
    float* outp = (dir ? outc : outr) + ((long)b * 512 + h * 64) * 64;
    __shared__ float qs[32][64], ks[32][64], vs[64][64], S[64][66];
    int tid = threadIdx.x;

    for (int e = tid; e < 2048; e += 256) {
        int c = e >> 6, i = e & 63;
        int gc = h * 32 + c;
        qs[c][i] = mean[((long)b * 1024 + gc) * 64 + i]       + interp_pe(peq, gc, i);
        ks[c][i] = mean[((long)b * 1024 + 256 + gc) * 64 + i] + interp_pe(pek, gc, i);
    }
    for (int e = tid; e < 4096; e += 256) {
        int dc = e >> 6, j = e & 63;
        vs[dc][j] = mean[((long)b * 1024 + 512 + h * 64 + dc) * 64 + j];
    }
    __syncthreads();
    const float scl = 0.17677669529663687f;
    for (int e = tid; e < 4096; e += 256) {
        int i = e >> 6, j = e & 63;
        float s = 0.f;
#pragma unroll
        for (int c = 0; c < 32; c++) s = fmaf(qs[c][i], ks[c][j], s);
        S[i][j] = s * scl;
    }
    __syncthreads();
    if (tid < 64) {
        int i = tid;
        float m = -1e30f;
        for (int j = 0; j < 64; j++) m = fmaxf(m, S[i][j]);
        float z = 0.f;
        for (int j = 0; j < 64; j++) { float e2 = __expf(S[i][j] - m); S[i][j] = e2; z += e2; }
        float inv = 1.f / z;
        for (int j = 0; j < 64; j++) S[i][j] *= inv;
    }
    __syncthreads();
    for (int e = tid; e < 4096; e += 256) {
        int dc = e >> 6, i = e & 63;
        float o = 0.f;
#pragma unroll
        for (int j = 0; j < 64; j++) o = fmaf(S[i][j], vs[dc][j], o);
        outp[dc * 64 + i] = o;
    }
}

// ======================= small fp32 GEMM (row/col attention projections) ==========
__global__ __launch_bounds__(256) void gemm1x1(
    const void* __restrict__ X, long x_b, int in_bf16,
    const float* __restrict__ W,
    const float* __restrict__ scale, const float* __restrict__ bias,
    void* __restrict__ out, long o_b, int out_bf16,
    int OC, int IC, int NP,
    int relu_in,
    const float* __restrict__ add_row, const float* __restrict__ add_col, long ar_b,
    int epi_mode, const float* __restrict__ mul_src, long mul_b,
    const float* __restrict__ s2, const float* __restrict__ b2)
{
    __shared__ __align__(16) float As[16][68];
    __shared__ __align__(16) float Bs[16][64];
    int b  = blockIdx.z;
    int oc0 = blockIdx.y * 64;
    int n0  = blockIdx.x * 64;
    int tid = threadIdx.x;
    int tx = tid & 15, ty = tid >> 4;
    float acc[4][4] = {};
    int y = n0 >> 6;

    for (int k0 = 0; k0 < IC; k0 += 16) {
#pragma unroll
        for (int l = 0; l < 4; l++) {
            int e = tid + l * 256;
            int oc = e >> 4, kk = e & 15;
            As[kk][oc] = W[(long)(oc0 + oc) * IC + (k0 + kk)];
        }
#pragma unroll
        for (int l = 0; l < 4; l++) {
            int e = tid + l * 256;
            int kk = e >> 6, n = e & 63;
            int ic = k0 + kk;
            long xi = (long)b * x_b + (long)ic * NP + (n0 + n);
            float v = in_bf16 ? __bfloat162float(((const bf16*)X)[xi])
                              : ((const float*)X)[xi];
            if (add_row)
                v += add_row[(long)b * ar_b + ic * 64 + y]
                   + add_col[(long)b * ar_b + ic * 64 + n];
            if (relu_in) v = fmaxf(v, 0.f);
            Bs[kk][n] = v;
        }
        __syncthreads();
#pragma unroll
        for (int kk = 0; kk < 16; kk++) {
            float a[4], bv[4];
            *(float4*)a  = *(const float4*)&As[kk][ty * 4];
            *(float4*)bv = *(const float4*)&Bs[kk][tx * 4];
#pragma unroll
            for (int i = 0; i < 4; i++)
#pragma unroll
                for (int j = 0; j < 4; j++)
                    acc[i][j] = fmaf(a[i], bv[j], acc[i][j]);
        }
        __syncthreads();
    }

#pragma unroll
    for (int i = 0; i < 4; i++) {
        int oc = oc0 + ty * 4 + i;
        float s  = scale ? scale[oc] : 1.f;
        float bb = bias  ? bias[oc]  : 0.f;
#pragma unroll
        for (int j = 0; j < 4; j++) {
            int n = n0 + tx * 4 + j;
            float v = fmaf(s, acc[i][j], bb);
            long oidx = (long)b * o_b + (long)oc * NP + n;
            if (epi_mode == 1) {
                float m = fmaf(s2[oc], mul_src[(long)b * mul_b + (long)oc * NP + n], b2[oc]);
                v = m / (1.f + __expf(-v));
            }
            if (out_bf16) ((bf16*)out)[oidx] = __float2bfloat16(v);
            else          ((float*)out)[oidx] = v;
        }
    }
}

// ======================= weight pre-contraction =======================
__global__ __launch_bounds__(256) void build_wga(
    const float* __restrict__ wq, const float* __restrict__ wk, const float* __restrict__ wv,
    const float* __restrict__ sq, const float* __restrict__ sk, const float* __restrict__ sv,
    const float* __restrict__ bq, const float* __restrict__ bk, const float* __restrict__ bv,
    const float* __restrict__ cov_s, const float* __restrict__ cov_b,
    float* __restrict__ Wga, float* __restrict__ beta)
{
    int idx = blockIdx.x * 256 + threadIdx.x;
    int ic = idx >> 8, i = idx & 255;
    const float* Wp; float sth, bth;
    if (ic < 256)      { Wp = wq + ic * 256;         sth = sq[ic];       bth = bq[ic]; }
    else if (ic < 512) { Wp = wk + (ic - 256) * 256; sth = sk[ic - 256]; bth = bk[ic - 256]; }
    else               { Wp = wv + (ic - 512) * 256; sth = sv[ic - 512]; bth = bv[ic - 512]; }
    Wga[idx] = cov_s[ic] * sth * Wp[i];
    if (i == 0) beta[ic] = cov_s[ic] * bth + cov_b[ic];
}

// N_t[oc][d*256 + i] bf16 = sum_ic kv[oc, ic, d] * Wga[ic, i]
__global__ __launch_bounds__(256) void build_N(
    const float* __restrict__ kvw, const float* __restrict__ Wga, bf16* __restrict__ Nt)
{
    int d = blockIdx.x >> 6, oc = blockIdx.x & 63;
    int i = threadIdx.x;
    float a = 0.f;
    for (int ic = 0; ic < 1024; ic++)
        a = fmaf(kvw[oc * 7168 + ic * 7 + d], Wga[ic * 256 + i], a);
    Nt[(long)oc * 1792 + d * 256 + i] = __float2bfloat16(a);
}

__global__ __launch_bounds__(64) void build_C(
    const float* __restrict__ kvw, const float* __restrict__ beta, float* __restrict__ C)
{
    int d = blockIdx.x, oc = threadIdx.x;
    float a = 0.f;
    for (int ic = 0; ic < 1024; ic++)
        a = fmaf(kvw[oc * 7168 + ic * 7 + d], beta[ic], a);
    C[d * 64 + oc] = a;
}

// M_t[o][d*64 + ic] bf16 = sum_c2 w_pw[o, c2] * kv[ic, c2, d]
__global__ __launch_bounds__(64) void build_M(
    const float* __restrict__ wpw, const float* __restrict__ kvw, bf16* __restrict__ Mt)
{
    int d = blockIdx.x >> 8, o = blockIdx.x & 255;
    int ic = threadIdx.x;
    float a = 0.f;
    for (int c2 = 0; c2 < 1024; c2++)
        a = fmaf(wpw[o * 1024 + c2], kvw[ic * 7168 + c2 * 7 + d], a);
    Mt[(long)o * 448 + d * 64 + ic] = __float2bfloat16(a);
}

// ======================= launch =======================
extern "C" void kernel_launch(void* const* d_in, const int* in_sizes, int n_in,
                              void* d_out, int out_size, void* d_ws, size_t ws_size,
                              hipStream_t stream)
{
    const float* x     = (const float*)d_in[0];
    const float* wq    = (const float*)d_in[1];
    const float* sq    = (const float*)d_in[2];
    const float* bq    = (const float*)d_in[3];
    const float* wk    = (const float*)d_in[4];
    const float* sk    = (const float*)d_in[5];
    const float* bk    = (const float*)d_in[6];
    const float* wv    = (const float*)d_in[7];
    const float* sv    = (const float*)d_in[8];
    const float* bv    = (const float*)d_in[9];
    const float* w_dw  = (const float*)d_in[10];
    const float* s_dw  = (const float*)d_in[11];
    const float* b_dw  = (const float*)d_in[12];
    const float* cov_s = (const float*)d_in[13];
    const float* cov_b = (const float*)d_in[14];
    const float* kv    = (const float*)d_in[15];
    const float* kv3   = (const float*)d_in[16];
    const float* w_pw  = (const float*)d_in[17];
    const float* s_pw  = (const float*)d_in[18];
    const float* b_pw  = (const float*)d_in[19];
    const float* w_row = (const float*)d_in[20];
    const float* s_row = (const float*)d_in[21];
    const float* b_row = (const float*)d_in[22];
    const float* w_col = (const float*)d_in[23];
    const float* s_col = (const float*)d_in[24];
    const float* b_col = (const float*)d_in[25];
    const float* w_proj= (const float*)d_in[26];
    const float* s_proj= (const float*)d_in[27];
    const float* b_proj= (const float*)d_in[28];
    const float* pe_rq = (const float*)d_in[29];
    const float* pe_rk = (const float*)d_in[30];
    const float* pe_cq = (const float*)d_in[31];
    const float* pe_ck = (const float*)d_in[32];
    float* out = (float*)d_out;

    char* wsb = (char*)d_ws;
    size_t off = 0;
    auto alloc = [&](size_t bytes) { char* p = wsb + off; off += (bytes + 255) & ~255UL; return p; };
    bf16*  qkv0   = (bf16*) alloc(67108864);    // (8,1024,4096) bf16
    bf16*  qkvpw  = (bf16*) alloc(16777216);    // (8,256,4096) bf16 raw pre-bn
    bf16*  x_t    = (bf16*) alloc(16777216);    // (8,4096,256) bf16
    bf16*  x1a    = (bf16*) alloc(4194304);     // (8,64,4096) bf16
    bf16*  x3a    = (bf16*) alloc(4194304);
    float* rowm   = (float*)alloc(2097152);     // (8,1024,64)
    float* colm   = (float*)alloc(2097152);
    float* atr    = (float*)alloc(1048576);     // (8,512,64)
    float* atc    = (float*)alloc(1048576);
    float* outr   = (float*)alloc(1048576);
    float* outc   = (float*)alloc(1048576);
    float* Wga    = (float*)alloc(1048576);     // (1024,256)
    float* beta   = (float*)alloc(4096);
    bf16*  Nv_t   = (bf16*) alloc(229376);      // (64,1792)
    bf16*  Nh_t   = (bf16*) alloc(229376);
    float* Cv     = (float*)alloc(1792);
    float* Ch     = (float*)alloc(1792);
    bf16*  Mv_t   = (bf16*) alloc(229376);      // (256,448)
    bf16*  Mh_t   = (bf16*) alloc(229376);
    bf16*  Wall   = (bf16*) alloc(524288);      // (1024,256)
    bf16*  wpw_bf = (bf16*) alloc(524288);      // (256,1024)
    bf16*  wproj_bf = (bf16*)alloc(262144);     // (256,512)
    float* sb_s   = (float*)alloc(4096);
    float* sb_b   = (float*)alloc(4096);
    if (off > ws_size) return;  // clean fail if workspace too small

    const long AB = 512L * 64;

    // ---- weight prep ----
    castw<<<2565, 256, 0, stream>>>(wq, wk, wv, sq, sk, sv, bq, bk, bv, w_pw, w_proj,
                                    Wall, wpw_bf, wproj_bf, sb_s, sb_b);
    cast_xt<<<dim3(64, 4, 8), 256, 0, stream>>>(x, x_t);
    build_wga<<<1024, 256, 0, stream>>>(wq, wk, wv, sq, sk, sv, bq, bk, bv, cov_s, cov_b, Wga, beta);
    build_N<<<448, 256, 0, stream>>>(kv,  Wga, Nv_t);
    build_N<<<448, 256, 0, stream>>>(kv3, Wga, Nh_t);
    build_C<<<7, 64, 0, stream>>>(kv,  beta, Cv);
    build_C<<<7, 64, 0, stream>>>(kv3, beta, Ch);
    build_M<<<1792, 64, 0, stream>>>(w_pw, kv,  Mv_t);
    build_M<<<1792, 64, 0, stream>>>(w_pw, kv3, Mh_t);

    // ---- qkv0 = bn(1x1 conv) via MFMA ----
    mfma_qkv<<<dim3(32, 8, 8), 256, 0, stream>>>(x_t, Wall, sb_s, sb_b, qkv0);

    // ---- squeeze attention ----
    meanrc<<<8192, 64, 0, stream>>>(qkv0, rowm, colm);
    attn_kernel<<<dim3(8, 8, 2), 256, 0, stream>>>(rowm, colm, pe_rq, pe_rk, pe_cq, pe_ck, atr, atc);
    gemm1x1<<<dim3(1, 8, 8), 256, 0, stream>>>(atr, AB, 0, w_row, s_row, b_row, outr, AB, 0, 512, 512, 64, 1, nullptr, nullptr, 0, 0, nullptr, 0, nullptr, nullptr);
    gemm1x1<<<dim3(1, 8, 8), 256, 0, stream>>>(atc, AB, 0, w_col, s_col, b_col, outc, AB, 0, 512, 512, 64, 1, nullptr, nullptr, 0, 0, nullptr, 0, nullptr, nullptr);

    // ---- stripe conv 1 (fused bn+qkv pre-contraction) + act_dn ----
    mstripe1<<<dim3(64, 8), 64, 0, stream>>>(x_t, Nv_t, Cv, x1a, 0);
    softmax_sp_bf<<<512, 256, 0, stream>>>(x1a);
    group_renorm_bf<<<1024, 256, 0, stream>>>(x1a);
    mstripe1<<<dim3(64, 8), 64, 0, stream>>>(x_t, Nh_t, Ch, x3a, 1);
    softmax_sp_bf<<<512, 256, 0, stream>>>(x3a);
    group_renorm_bf<<<1024, 256, 0, stream>>>(x3a);

    // ---- pw conv with fused dw3x3 (bn deferred) + stripe conv 2 via w_pw ----
    mfma_pw_dw<<<dim3(32, 2, 8), 256, 0, stream>>>(qkv0, wpw_bf, w_dw, s_dw, b_dw, qkvpw);
    mstripe2<<<dim3(32, 2, 8), 256, 0, stream>>>(x1a, Mv_t, qkvpw, 0);
    mstripe2<<<dim3(32, 2, 8), 256, 0, stream>>>(x3a, Mh_t, qkvpw, 1);

    // ---- final proj with fused epilogue ----
    mfma_proj<<<dim3(32, 2, 8), 256, 0, stream>>>(qkv0, wproj_bf, outr, outc,
                                                  s_proj, b_proj, qkvpw, s_pw, b_pw, out);
}

// Round 4
// 1035.308 us; speedup vs baseline: 3.6907x; 1.3218x over previous
//
#include <hip/hip_runtime.h>
#include <hip/hip_bf16.h>
#include <math.h>

#define HW 4096
typedef __hip_bfloat16 bf16;
typedef __attribute__((ext_vector_type(8))) short bfrag;
typedef __attribute__((ext_vector_type(4))) float ffrag;

__device__ __forceinline__ float bf2f(short u) {
    return __uint_as_float(((unsigned)(unsigned short)u) << 16);
}
__device__ __forceinline__ short f2bfs(float v) {
    bf16 h = __float2bfloat16(v);
    return *reinterpret_cast<short*>(&h);
}

// ======================= cast + transpose x: [256][4096] -> [4096][256] bf16 ==========
__global__ __launch_bounds__(256) void cast_xt(const float* __restrict__ x, bf16* __restrict__ xt)
{
    __shared__ float t[64][65];
    int b = blockIdx.z, it = blockIdx.y, pt = blockIdx.x;
    int ic0 = it * 64, px0 = pt * 64;
    int tid = threadIdx.x;
    for (int l = 0; l < 16; l++) {
        int e = tid + l * 256;
        int px = e & 63, ic = e >> 6;
        t[ic][px] = x[((long)b * 256 + ic0 + ic) * HW + px0 + px];
    }
    __syncthreads();
    for (int l = 0; l < 16; l++) {
        int e = tid + l * 256;
        int ic = e & 63, px = e >> 6;
        xt[((long)b * HW + px0 + px) * 256 + ic0 + ic] = __float2bfloat16(t[ic][px]);
    }
}

// ======================= weight casts ==========
__global__ __launch_bounds__(256) void castw(
    const float* __restrict__ wq, const float* __restrict__ wk, const float* __restrict__ wv,
    const float* __restrict__ sq, const float* __restrict__ sk, const float* __restrict__ sv,
    const float* __restrict__ bq, const float* __restrict__ bk, const float* __restrict__ bv,
    const float* __restrict__ w_pw, const float* __restrict__ w_proj,
    bf16* __restrict__ Wall, bf16* __restrict__ wpw_bf, bf16* __restrict__ wproj_bf,
    float* __restrict__ sb_s, float* __restrict__ sb_b)
{
    int idx = blockIdx.x * 256 + threadIdx.x;
    if (idx < 262144) {
        int oc = idx >> 8, i = idx & 255;
        float v;
        if (oc < 256) v = wq[oc * 256 + i];
        else if (oc < 512) v = wk[(oc - 256) * 256 + i];
        else v = wv[(oc - 512) * 256 + i];
        Wall[idx] = __float2bfloat16(v);
        return;
    }
    idx -= 262144;
    if (idx < 262144) { wpw_bf[idx] = __float2bfloat16(w_pw[idx]); return; }
    idx -= 262144;
    if (idx < 131072) { wproj_bf[idx] = __float2bfloat16(w_proj[idx]); return; }
    idx -= 131072;
    if (idx < 1024) {
        int oc = idx;
        float s, bb;
        if (oc < 256) { s = sq[oc]; bb = bq[oc]; }
        else if (oc < 512) { s = sk[oc - 256]; bb = bk[oc - 256]; }
        else { s = sv[oc - 512]; bb = bv[oc - 512]; }
        sb_s[oc] = s; sb_b[oc] = bb;
    }
}

// ======================= MFMA qkv GEMM: qkv0[b][1024][4096] = bn(Wall x) ==========
__global__ __launch_bounds__(256) void mfma_qkv(
    const bf16* __restrict__ Xt, const bf16* __restrict__ Wall,
    const float* __restrict__ sb_s, const float* __restrict__ sb_b,
    bf16* __restrict__ qkv0)
{
    __shared__ __align__(16) short As[128 * 40];
    __shared__ __align__(16) short Bs[128 * 40];
    int b = blockIdx.z, mt = blockIdx.y, nt = blockIdx.x;
    int oc0 = mt * 128, n0 = nt * 128;
    int tid = threadIdx.x;
    int lane = tid & 63, wave = tid >> 6;
    int lr = lane & 15, quad = lane >> 4;
    int wm = (wave & 1) * 64, wn = (wave >> 1) * 64;
    ffrag acc[4][4];
#pragma unroll
    for (int i = 0; i < 4; i++)
#pragma unroll
        for (int j = 0; j < 4; j++)
#pragma unroll
            for (int r = 0; r < 4; r++) acc[i][j][r] = 0.f;

    for (int k0 = 0; k0 < 256; k0 += 32) {
#pragma unroll
        for (int l = 0; l < 2; l++) {
            int e = tid + l * 256;
            int r = e >> 2, c = e & 3;
            *(int4*)&As[r * 40 + c * 8] = *(const int4*)&Wall[(long)(oc0 + r) * 256 + k0 + c * 8];
            *(int4*)&Bs[r * 40 + c * 8] = *(const int4*)&Xt[((long)b * HW + n0 + r) * 256 + k0 + c * 8];
        }
        __syncthreads();
        bfrag a[4], bb[4];
#pragma unroll
        for (int i = 0; i < 4; i++) a[i]  = *(const bfrag*)&As[(wm + i * 16 + lr) * 40 + quad * 8];
#pragma unroll
        for (int j = 0; j < 4; j++) bb[j] = *(const bfrag*)&Bs[(wn + j * 16 + lr) * 40 + quad * 8];
#pragma unroll
        for (int i = 0; i < 4; i++)
#pragma unroll
            for (int j = 0; j < 4; j++)
                acc[i][j] = __builtin_amdgcn_mfma_f32_16x16x32_bf16(a[i], bb[j], acc[i][j], 0, 0, 0);
        __syncthreads();
    }
#pragma unroll
    for (int i = 0; i < 4; i++)
#pragma unroll
        for (int r = 0; r < 4; r++) {
            int row = oc0 + wm + i * 16 + quad * 4 + r;
            float s = sb_s[row], bb2 = sb_b[row];
#pragma unroll
            for (int j = 0; j < 4; j++) {
                int col = n0 + wn + j * 16 + lr;
                qkv0[((long)b * 1024 + row) * HW + col] = __float2bfloat16(fmaf(s, acc[i][j][r], bb2));
            }
        }
}

// ======================= MFMA pw GEMM with fused dw3x3+bn+relu B ==========
__global__ __launch_bounds__(256) void mfma_pw_dw(
    const bf16* __restrict__ qkv0, const bf16* __restrict__ wpw_bf,
    const float* __restrict__ w_dw, const float* __restrict__ s_dw, const float* __restrict__ b_dw,
    bf16* __restrict__ qkvpw)
{
    __shared__ __align__(16) short As[128 * 40];
    __shared__ __align__(16) short Bst[32 * 136];
    int b = blockIdx.z, mt = blockIdx.y, nt = blockIdx.x;
    int oc0 = mt * 128, y0 = nt * 2, px0 = nt * 128;
    int tid = threadIdx.x;
    int lane = tid & 63, wave = tid >> 6;
    int lr = lane & 15, quad = lane >> 4;
    int wm = (wave & 1) * 64, wn = (wave >> 1) * 64;
    int dc = tid >> 3;            // 0..31 channel within slab
    int ux = tid & 7;             // 0..7 -> px = ux*16..+16
    int drow = ux >> 2;           // output row 0/1
    int xb = (ux & 3) * 16;       // x base
    ffrag acc[4][4];
#pragma unroll
    for (int i = 0; i < 4; i++)
#pragma unroll
        for (int j = 0; j < 4; j++)
#pragma unroll
            for (int r = 0; r < 4; r++) acc[i][j][r] = 0.f;

    for (int k0 = 0; k0 < 1024; k0 += 32) {
#pragma unroll
        for (int l = 0; l < 2; l++) {
            int e = tid + l * 256;
            int r = e >> 2, c = e & 3;
            *(int4*)&As[r * 40 + c * 8] = *(const int4*)&wpw_bf[(long)(oc0 + r) * 1024 + k0 + c * 8];
        }
        {
            int ch = k0 + dc;
            float wd[9];
#pragma unroll
            for (int t = 0; t < 9; t++) wd[t] = w_dw[ch * 9 + t];
            float o16[16];
#pragma unroll
            for (int t = 0; t < 16; t++) o16[t] = 0.f;
            const bf16* base = qkv0 + ((long)b * 1024 + ch) * HW;
#pragma unroll
            for (int dy = 0; dy < 3; dy++) {
                int gr = y0 + drow + dy - 1;
                float w[18];
                if (gr >= 0 && gr < 64) {
                    short ck[4][8];
#pragma unroll
                    for (int c4 = 0; c4 < 4; c4++) {
                        int xcol = xb - 8 + c4 * 8;
                        if (xcol >= 0 && xcol <= 56)
                            *(int4*)ck[c4] = *(const int4*)&base[gr * 64 + xcol];
                        else {
                            int4 z = {0, 0, 0, 0};
                            *(int4*)ck[c4] = z;
                        }
                    }
#pragma unroll
                    for (int t = 0; t < 18; t++)
                        w[t] = bf2f(ck[(t + 7) >> 3][(t + 7) & 7]);
                } else {
#pragma unroll
                    for (int t = 0; t < 18; t++) w[t] = 0.f;
                }
#pragma unroll
                for (int dx = 0; dx < 3; dx++) {
                    float wt = wd[dy * 3 + dx];
#pragma unroll
                    for (int o = 0; o < 16; o++)
                        o16[o] = fmaf(wt, w[o + dx], o16[o]);
                }
            }
            float ss = s_dw[ch], bb0 = b_dw[ch];
            short pk[16];
#pragma unroll
            for (int o = 0; o < 16; o++)
                pk[o] = f2bfs(fmaxf(fmaf(ss, o16[o], bb0), 0.f));
            *(int4*)&Bst[dc * 136 + ux * 16]     = *(int4*)&pk[0];
            *(int4*)&Bst[dc * 136 + ux * 16 + 8] = *(int4*)&pk[8];
        }
        __syncthreads();
        bfrag a[4], bb[4];
#pragma unroll
        for (int i = 0; i < 4; i++) a[i] = *(const bfrag*)&As[(wm + i * 16 + lr) * 40 + quad * 8];
#pragma unroll
        for (int j = 0; j < 4; j++) {
            int col = wn + j * 16 + lr;
#pragma unroll
            for (int e = 0; e < 8; e++) bb[j][e] = Bst[(quad * 8 + e) * 136 + col];
        }
#pragma unroll
        for (int i = 0; i < 4; i++)
#pragma unroll
            for (int j = 0; j < 4; j++)
                acc[i][j] = __builtin_amdgcn_mfma_f32_16x16x32_bf16(a[i], bb[j], acc[i][j], 0, 0, 0);
        __syncthreads();
    }
#pragma unroll
    for (int i = 0; i < 4; i++)
#pragma unroll
        for (int r = 0; r < 4; r++) {
            int row = oc0 + wm + i * 16 + quad * 4 + r;
#pragma unroll
            for (int j = 0; j < 4; j++) {
                int col = px0 + wn + j * 16 + lr;
                qkvpw[((long)b * 256 + row) * HW + col] = __float2bfloat16(acc[i][j][r]);
            }
        }
}

// ======================= MFMA proj GEMM with fused epilogue ==========
__global__ __launch_bounds__(256) void mfma_proj(
    const bf16* __restrict__ qkv0, const bf16* __restrict__ wproj_bf,
    const float* __restrict__ outr, const float* __restrict__ outc,
    const float* __restrict__ s_proj, const float* __restrict__ b_proj,
    const bf16* __restrict__ qkvpw, const float* __restrict__ s_pw, const float* __restrict__ b_pw,
    float* __restrict__ out)
{
    __shared__ __align__(16) short As[128 * 40];
    __shared__ __align__(16) short Bst[32 * 136];
    int b = blockIdx.z, mt = blockIdx.y, nt = blockIdx.x;
    int oc0 = mt * 128, y0 = nt * 2, px0 = nt * 128;
    int tid = threadIdx.x;
    int lane = tid & 63, wave = tid >> 6;
    int lr = lane & 15, quad = lane >> 4;
    int wm = (wave & 1) * 64, wn = (wave >> 1) * 64;
    ffrag acc[4][4];
#pragma unroll
    for (int i = 0; i < 4; i++)
#pragma unroll
        for (int j = 0; j < 4; j++)
#pragma unroll
            for (int r = 0; r < 4; r++) acc[i][j][r] = 0.f;

    for (int k0 = 0; k0 < 512; k0 += 32) {
#pragma unroll
        for (int l = 0; l < 2; l++) {
            int e = tid + l * 256;
            int r = e >> 2, c = e & 3;
            *(int4*)&As[r * 40 + c * 8] = *(const int4*)&wproj_bf[(long)(oc0 + r) * 512 + k0 + c * 8];
        }
#pragma unroll
        for (int l = 0; l < 2; l++) {
            int e = tid + l * 256;
            int cx = e & 15, c = e >> 4;
            int dh = k0 + c;
            short v8[8];
            *(int4*)v8 = *(const int4*)&qkv0[((long)b * 1024 + 512 + dh) * HW + px0 + cx * 8];
            int yy = y0 + (cx >> 3);
            float ro = outr[((long)b * 512 + dh) * 64 + yy];
            const float* cbase = &outc[((long)b * 512 + dh) * 64];
            short pk[8];
#pragma unroll
            for (int p = 0; p < 8; p++) {
                int pxl = cx * 8 + p;
                float val = bf2f(v8[p]) + ro + cbase[pxl & 63];
                pk[p] = f2bfs(fmaxf(val, 0.f));
            }
            *(int4*)&Bst[c * 136 + cx * 8] = *(int4*)pk;
        }
        __syncthreads();
        bfrag a[4], bb[4];
#pragma unroll
        for (int i = 0; i < 4; i++) a[i] = *(const bfrag*)&As[(wm + i * 16 + lr) * 40 + quad * 8];
#pragma unroll
        for (int j = 0; j < 4; j++) {
            int col = wn + j * 16 + lr;
#pragma unroll
            for (int e = 0; e < 8; e++) bb[j][e] = Bst[(quad * 8 + e) * 136 + col];
        }
#pragma unroll
        for (int i = 0; i < 4; i++)
#pragma unroll
            for (int j = 0; j < 4; j++)
                acc[i][j] = __builtin_amdgcn_mfma_f32_16x16x32_bf16(a[i], bb[j], acc[i][j], 0, 0, 0);
        __syncthreads();
    }
#pragma unroll
    for (int i = 0; i < 4; i++)
#pragma unroll
        for (int r = 0; r < 4; r++) {
            int row = oc0 + wm + i * 16 + quad * 4 + r;
            float sp = s_proj[row], bp = b_proj[row];
            float sw = s_pw[row], bw = b_pw[row];
#pragma unroll
            for (int j = 0; j < 4; j++) {
                int col = px0 + wn + j * 16 + lr;
                long idx = ((long)b * 256 + row) * HW + col;
                float t = fmaf(sp, acc[i][j][r], bp);
                float m = fmaf(sw, bf2f(*(const short*)&qkvpw[idx]), bw);
                out[idx] = m / (1.f + __expf(-t));
            }
        }
}

// ======================= MFMA stripe conv 1 v2: 4 waves, 1 y-row each ==========
// out[b][64][4096] bf16;  dir 0: vertical 7x1, dir 1: horizontal 1x7
__global__ __launch_bounds__(256) void mstripe1(
    const bf16* __restrict__ xt, const bf16* __restrict__ Nt, const float* __restrict__ C,
    bf16* __restrict__ outp, int dir)
{
    __shared__ __align__(16) short As[64 * 264];
    int b = blockIdx.y;
    int tid = threadIdx.x;
    int wave = tid >> 6, lane = tid & 63;
    int lr = lane & 15, quad = lane >> 4;
    int y = blockIdx.x * 4 + wave;
    ffrag acc[4][4];
#pragma unroll
    for (int i = 0; i < 4; i++)
#pragma unroll
        for (int j = 0; j < 4; j++)
#pragma unroll
            for (int r = 0; r < 4; r++) acc[i][j][r] = 0.f;
    bfrag zf;
#pragma unroll
    for (int e = 0; e < 8; e++) zf[e] = 0;

    for (int d = 0; d < 7; d++) {
        __syncthreads();
#pragma unroll
        for (int l = 0; l < 8; l++) {
            int e = tid + l * 256;          // 0..2047 int4 chunks
            int oc = e >> 5, c = e & 31;
            *(int4*)&As[oc * 264 + c * 8] = *(const int4*)&Nt[(long)oc * 1792 + d * 256 + c * 8];
        }
        __syncthreads();
        int off = d - 3;
        int row = y + off;
        bool vrow = (row >= 0 && row < 64);
        for (int ks = 0; ks < 8; ks++) {
            bfrag a[4], bb[4];
#pragma unroll
            for (int i = 0; i < 4; i++)
                a[i] = *(const bfrag*)&As[(i * 16 + lr) * 264 + ks * 32 + quad * 8];
#pragma unroll
            for (int j = 0; j < 4; j++) {
                int x = j * 16 + lr;
                if (dir == 0) {
                    bb[j] = vrow ? *(const bfrag*)&xt[((long)b * HW + row * 64 + x) * 256 + ks * 32 + quad * 8] : zf;
                } else {
                    int xs = x + off;
                    bb[j] = (xs >= 0 && xs < 64)
                        ? *(const bfrag*)&xt[((long)b * HW + y * 64 + xs) * 256 + ks * 32 + quad * 8] : zf;
                }
            }
#pragma unroll
            for (int i = 0; i < 4; i++)
#pragma unroll
                for (int j = 0; j < 4; j++)
                    acc[i][j] = __builtin_amdgcn_mfma_f32_16x16x32_bf16(a[i], bb[j], acc[i][j], 0, 0, 0);
        }
    }
#pragma unroll
    for (int i = 0; i < 4; i++)
#pragma unroll
        for (int r = 0; r < 4; r++) {
            int oc = i * 16 + quad * 4 + r;
#pragma unroll
            for (int j = 0; j < 4; j++) {
                int x = j * 16 + lr;
                float ct = 0.f;
                int base = dir ? x : y;
                for (int d = 0; d < 7; d++) {
                    int t = base + d - 3;
                    if (t >= 0 && t < 64) ct += C[d * 64 + oc];
                }
                outp[((long)b * 64 + oc) * HW + y * 64 + x] = __float2bfloat16(acc[i][j][r] + ct);
            }
        }
}

// ======================= MFMA stripe conv 2 (through w_pw), accumulate into qkvpw ==========
__global__ __launch_bounds__(256) void mstripe2(
    const bf16* __restrict__ inp, const bf16* __restrict__ Mt,
    bf16* __restrict__ qkvpw, int dir)
{
    __shared__ __align__(16) short As[128 * 40];
    __shared__ __align__(16) short Bst[32 * 136];
    int b = blockIdx.z, mt = blockIdx.y, nt = blockIdx.x;
    int oc0 = mt * 128, y0 = nt * 2, px0 = nt * 128;
    int tid = threadIdx.x;
    int lane = tid & 63, wave = tid >> 6;
    int lr = lane & 15, quad = lane >> 4;
    int wm = (wave & 1) * 64, wn = (wave >> 1) * 64;
    ffrag acc[4][4];
#pragma unroll
    for (int i = 0; i < 4; i++)
#pragma unroll
        for (int j = 0; j < 4; j++)
#pragma unroll
            for (int r = 0; r < 4; r++) acc[i][j][r] = 0.f;

    for (int d = 0; d < 7; d++) {
        int off = d - 3;
        for (int ks = 0; ks < 2; ks++) {
#pragma unroll
            for (int l = 0; l < 2; l++) {
                int e = tid + l * 256;
                int r = e >> 2, cc = e & 3;
                *(int4*)&As[r * 40 + cc * 8] = *(const int4*)&Mt[(long)(oc0 + r) * 448 + d * 64 + ks * 32 + cc * 8];
            }
#pragma unroll
            for (int l = 0; l < 2; l++) {
                int e = tid + l * 256;
                int cx = e & 15, c = e >> 4;
                int ic = ks * 32 + c;
                int rloc = cx >> 3;
                const bf16* src = &inp[((long)b * 64 + ic) * HW];
                if (dir == 0) {
                    int srow = y0 + rloc + off;
                    int4 v;
                    if (srow >= 0 && srow < 64)
                        v = *(const int4*)&src[srow * 64 + (cx & 7) * 8];
                    else { int4 z = {0,0,0,0}; v = z; }
                    *(int4*)&Bst[c * 136 + cx * 8] = v;
                } else {
                    short pk[8];
#pragma unroll
                    for (int p = 0; p < 8; p++) {
                        int xl = (cx & 7) * 8 + p;
                        int xs = xl + off;
                        pk[p] = (xs >= 0 && xs < 64) ? *(const short*)&src[(y0 + rloc) * 64 + xs] : (short)0;
                    }
                    *(int4*)&Bst[c * 136 + cx * 8] = *(int4*)pk;
                }
            }
            __syncthreads();
            bfrag a[4], bb[4];
#pragma unroll
            for (int i = 0; i < 4; i++) a[i] = *(const bfrag*)&As[(wm + i * 16 + lr) * 40 + quad * 8];
#pragma unroll
            for (int j = 0; j < 4; j++) {
                int col = wn + j * 16 + lr;
#pragma unroll
                for (int e = 0; e < 8; e++) bb[j][e] = Bst[(quad * 8 + e) * 136 + col];
            }
#pragma unroll
            for (int i = 0; i < 4; i++)
#pragma unroll
                for (int j = 0; j < 4; j++)
                    acc[i][j] = __builtin_amdgcn_mfma_f32_16x16x32_bf16(a[i], bb[j], acc[i][j], 0, 0, 0);
            __syncthreads();
        }
    }
#pragma unroll
    for (int i = 0; i < 4; i++)
#pragma unroll
        for (int r = 0; r < 4; r++) {
            int row = oc0 + wm + i * 16 + quad * 4 + r;
#pragma unroll
            for (int j = 0; j < 4; j++) {
                int col = px0 + wn + j * 16 + lr;
                long idx = ((long)b * 256 + row) * HW + col;
                float v = bf2f(*(const short*)&qkvpw[idx]) + acc[i][j][r];
                qkvpw[idx] = __float2bfloat16(v);
            }
        }
}

// ======================= act_dn (bf16) =======================
__global__ __launch_bounds__(256) void softmax_sp_bf(bf16* __restrict__ x)
{
    __shared__ float red[4];
    bf16* p = x + (long)blockIdx.x * HW;
    int tid = threadIdx.x;
    float m = -1e30f;
    for (int i = tid; i < HW; i += 256) m = fmaxf(m, __bfloat162float(p[i]));
    for (int o = 32; o > 0; o >>= 1) m = fmaxf(m, __shfl_down(m, o));
    if ((tid & 63) == 0) red[tid >> 6] = m;
    __syncthreads();
    m = fmaxf(fmaxf(red[0], red[1]), fmaxf(red[2], red[3]));
    __syncthreads();
    float z = 0.f;
    for (int i = tid; i < HW; i += 256) z += __expf(__bfloat162float(p[i]) - m);
    for (int o = 32; o > 0; o >>= 1) z += __shfl_down(z, o);
    if ((tid & 63) == 0) red[tid >> 6] = z;
    __syncthreads();
    z = red[0] + red[1] + red[2] + red[3];
    float inv = 1.f / z;
    for (int i = tid; i < HW; i += 256)
        p[i] = __float2bfloat16(__expf(__bfloat162float(p[i]) - m) * inv);
}

__global__ __launch_bounds__(256) void group_renorm_bf(bf16* __restrict__ x)
{
    long t = (long)blockIdx.x * 256 + threadIdx.x;   // B*8*4096
    int s = (int)(t & 4095);
    int h = (int)((t >> 12) & 7);
    int b = (int)(t >> 15);
    bf16* base = x + (((long)(b * 64 + h * 8)) << 12) + s;
    float v[8]; float g = 0.f;
#pragma unroll
    for (int j = 0; j < 8; j++) { v[j] = __bfloat162float(base[(long)j << 12]); g += v[j]; }
    float inv = 1.f / (g + 1e-6f);
#pragma unroll
    for (int j = 0; j < 8; j++) base[(long)j << 12] = __float2bfloat16(v[j] * inv);
}

// ======================= row/col means of qkv0 (bf16) =======================
__global__ __launch_bounds__(64) void meanrc(
    const bf16* __restrict__ in, float* __restrict__ rowm, float* __restrict__ colm)
{
    __shared__ float tile[64][65];
    int bc = blockIdx.x;
    const bf16* p = in + (long)bc * HW;
    int t = threadIdx.x;
    for (int i = 0; i < 64; i++) tile[i][t] = __bfloat162float(p[i * 64 + t]);
    __syncthreads();
    float rs = 0.f, cs = 0.f;
    for (int i = 0; i < 64; i++) { rs += tile[t][i]; cs += tile[i][t]; }
    rowm[(long)bc * 64 + t] = rs * (1.f / 64.f);
    colm[(long)bc * 64 + t] = cs * (1.f / 64.f);
}

// ======================= squeeze attention =======================
__device__ __forceinline__ float interp_pe(const float* pe, int c, int i)
{
    float coord = fminf(fmaxf((i + 0.5f) * 0.25f - 0.5f, 0.f), 15.f);
    int lo = (int)coord;
    int hi = min(lo + 1, 15);
    float t = coord - (float)lo;
    return pe[c * 16 + lo] * (1.f - t) + pe[c * 16 + hi] * t;
}

__global__ __launch_bounds__(256) void attn_kernel(
    const float* __restrict__ rowm, const float* __restrict__ colm,
    const float* __restrict__ pe_rq, const float* __restrict__ pe_rk,
    const float* __restrict__ pe_cq, const float* __restrict__ pe_ck,
    float* __restrict__ outr, float* __restrict__ outc)
{
    int h = blockIdx.x, b = blockIdx.y, dir = blockIdx.z;
    const float* mean = dir ? colm : rowm;
    const float* peq = dir ? pe_cq : pe_rq;
    const float* pek = dir ? pe_ck : pe_rk;
    float* outp = (dir ? outc : outr) + ((long)b * 512 + h * 64) * 64;
    __shared__ float qs[32][64], ks[32][64], vs[64][64], S[64][66];
    int tid = threadIdx.x;

    for (int e = tid; e < 2048; e += 256) {
        int c = e >> 6, i = e & 63;
        int gc = h * 32 + c;
        qs[c][i] = mean[((long)b * 1024 + gc) * 64 + i]       + interp_pe(peq, gc, i);
        ks[c][i] = mean[((long)b * 1024 + 256 + gc) * 64 + i] + interp_pe(pek, gc, i);
    }
    for (int e = tid; e < 4096; e += 256) {
        int dc = e >> 6, j = e & 63;
        vs[dc][j] = mean[((long)b * 1024 + 512 + h * 64 + dc) * 64 + j];
    }
    __syncthreads();
    const float scl = 0.17677669529663687f;
    for (int e = tid; e < 4096; e += 256) {
        int i = e >> 6, j = e & 63;
        float s = 0.f;
#pragma unroll
        for (int c = 0; c < 32; c++) s = fmaf(qs[c][i], ks[c][j], s);
        S[i][j] = s * scl;
    }
    __syncthreads();
    if (tid < 64) {
        int i = tid;
        float m = -1e30f;
        for (int j = 0; j < 64; j++) m = fmaxf(m, S[i][j]);
        float z = 0.f;
        for (int j = 0; j < 64; j++) { float e2 = __expf(S[i][j] - m); S[i][j] = e2; z += e2; }
        float inv = 1.f / z;
        for (int j = 0; j < 64; j++) S[i][j] *= inv;
    }
    __syncthreads();
    for (int e = tid; e < 4096; e += 256) {
        int dc = e >> 6, i = e & 63;
        float o = 0.f;
#pragma unroll
        for (int j = 0; j < 64; j++) o = fmaf(S[i][j], vs[dc][j], o);
        outp[dc * 64 + i] = o;
    }
}

// ======================= small fp32 GEMM (row/col attention projections) ==========
__global__ __launch_bounds__(256) void gemm1x1(
    const void* __restrict__ X, long x_b, int in_bf16,
    const float* __restrict__ W,
    const float* __restrict__ scale, const float* __restrict__ bias,
    void* __restrict__ out, long o_b, int out_bf16,
    int OC, int IC, int NP,
    int relu_in,
    const float* __restrict__ add_row, const float* __restrict__ add_col, long ar_b,
    int epi_mode, const float* __restrict__ mul_src, long mul_b,
    const float* __restrict__ s2, const float* __restrict__ b2)
{
    __shared__ __align__(16) float As[16][68];
    __shared__ __align__(16) float Bs[16][64];
    int b  = blockIdx.z;
    int oc0 = blockIdx.y * 64;
    int n0  = blockIdx.x * 64;
    int tid = threadIdx.x;
    int tx = tid & 15, ty = tid >> 4;
    float acc[4][4] = {};
    int y = n0 >> 6;

    for (int k0 = 0; k0 < IC; k0 += 16) {
#pragma unroll
        for (int l = 0; l < 4; l++) {
            int e = tid + l * 256;
            int oc = e >> 4, kk = e & 15;
            As[kk][oc] = W[(long)(oc0 + oc) * IC + (k0 + kk)];
        }
#pragma unroll
        for (int l = 0; l < 4; l++) {
            int e = tid + l * 256;
            int kk = e >> 6, n = e & 63;
            int ic = k0 + kk;
            long xi = (long)b * x_b + (long)ic * NP + (n0 + n);
            float v = in_bf16 ? __bfloat162float(((const bf16*)X)[xi])
                              : ((const float*)X)[xi];
            if (add_row)
                v += add_row[(long)b * ar_b + ic * 64 + y]
                   + add_col[(long)b * ar_b + ic * 64 + n];
            if (relu_in) v = fmaxf(v, 0.f);
            Bs[kk][n] = v;
        }
        __syncthreads();
#pragma unroll
        for (int kk = 0; kk < 16; kk++) {
            float a[4], bv[4];
            *(float4*)a  = *(const float4*)&As[kk][ty * 4];
            *(float4*)bv = *(const float4*)&Bs[kk][tx * 4];
#pragma unroll
            for (int i = 0; i < 4; i++)
#pragma unroll
                for (int j = 0; j < 4; j++)
                    acc[i][j] = fmaf(a[i], bv[j], acc[i][j]);
        }
        __syncthreads();
    }

#pragma unroll
    for (int i = 0; i < 4; i++) {
        int oc = oc0 + ty * 4 + i;
        float s  = scale ? scale[oc] : 1.f;
        float bb = bias  ? bias[oc]  : 0.f;
#pragma unroll
        for (int j = 0; j < 4; j++) {
            int n = n0 + tx * 4 + j;
            float v = fmaf(s, acc[i][j], bb);
            long oidx = (long)b * o_b + (long)oc * NP + n;
            if (epi_mode == 1) {
                float m = fmaf(s2[oc], mul_src[(long)b * mul_b + (long)oc * NP + n], b2[oc]);
                v = m / (1.f + __expf(-v));
            }
            if (out_bf16) ((bf16*)out)[oidx] = __float2bfloat16(v);
            else          ((float*)out)[oidx] = v;
        }
    }
}

// ======================= weight pre-contraction =======================
__global__ __launch_bounds__(256) void build_wga(
    const float* __restrict__ wq, const float* __restrict__ wk, const float* __restrict__ wv,
    const float* __restrict__ sq, const float* __restrict__ sk, const float* __restrict__ sv,
    const float* __restrict__ bq, const float* __restrict__ bk, const float* __restrict__ bv,
    const float* __restrict__ cov_s, const float* __restrict__ cov_b,
    float* __restrict__ Wga, float* __restrict__ beta)
{
    int idx = blockIdx.x * 256 + threadIdx.x;
    int ic = idx >> 8, i = idx & 255;
    const float* Wp; float sth, bth;
    if (ic < 256)      { Wp = wq + ic * 256;         sth = sq[ic];       bth = bq[ic]; }
    else if (ic < 512) { Wp = wk + (ic - 256) * 256; sth = sk[ic - 256]; bth = bk[ic - 256]; }
    else               { Wp = wv + (ic - 512) * 256; sth = sv[ic - 512]; bth = bv[ic - 512]; }
    Wga[idx] = cov_s[ic] * sth * Wp[i];
    if (i == 0) beta[ic] = cov_s[ic] * bth + cov_b[ic];
}

// N_t[oc][d*256 + i] bf16 = sum_ic kv[oc, ic, d] * Wga[ic, i]
__global__ __launch_bounds__(256) void build_N(
    const float* __restrict__ kvw, const float* __restrict__ Wga, bf16* __restrict__ Nt)
{
    int d = blockIdx.x >> 6, oc = blockIdx.x & 63;
    int i = threadIdx.x;
    float a = 0.f;
    for (int ic = 0; ic < 1024; ic++)
        a = fmaf(kvw[oc * 7168 + ic * 7 + d], Wga[ic * 256 + i], a);
    Nt[(long)oc * 1792 + d * 256 + i] = __float2bfloat16(a);
}

__global__ __launch_bounds__(64) void build_C(
    const float* __restrict__ kvw, const float* __restrict__ beta, float* __restrict__ C)
{
    int d = blockIdx.x, oc = threadIdx.x;
    float a = 0.f;
    for (int ic = 0; ic < 1024; ic++)
        a = fmaf(kvw[oc * 7168 + ic * 7 + d], beta[ic], a);
    C[d * 64 + oc] = a;
}

// ======== kv transpose: kvT2[c2][d*64+ic] = kv[ic][c2][d] ========
__global__ __launch_bounds__(256) void kv_transpose(
    const float* __restrict__ kvw, float* __restrict__ kvT2)
{
    int idx = blockIdx.x * 256 + threadIdx.x;    // 1024*448
    if (idx >= 458752) return;
    int c2 = idx / 448;
    int rem = idx - c2 * 448;
    int d = rem >> 6, ic = rem & 63;
    kvT2[idx] = kvw[ic * 7168 + c2 * 7 + d];
}

// M_t[o][d*64 + ic] = sum_c2 wpw[o][c2] * kvT2[c2][d*64+ic]  (coalesced)
__global__ __launch_bounds__(256) void build_M2(
    const float* __restrict__ wpw, const float* __restrict__ kvT2, bf16* __restrict__ Mt)
{
    int d = blockIdx.x % 7, og = blockIdx.x / 7;    // og 0..63
    int o = og * 4 + (threadIdx.x >> 6);
    int ic = threadIdx.x & 63;
    const float* kp = kvT2 + d * 64 + ic;
    const float* wp = wpw + (long)o * 1024;
    float a = 0.f;
#pragma unroll 8
    for (int c2 = 0; c2 < 1024; c2++)
        a = fmaf(wp[c2], kp[(long)c2 * 448], a);
    Mt[(long)o * 448 + d * 64 + ic] = __float2bfloat16(a);
}

// ======================= launch =======================
extern "C" void kernel_launch(void* const* d_in, const int* in_sizes, int n_in,
                              void* d_out, int out_size, void* d_ws, size_t ws_size,
                              hipStream_t stream)
{
    const float* x     = (const float*)d_in[0];
    const float* wq    = (const float*)d_in[1];
    const float* sq    = (const float*)d_in[2];
    const float* bq    = (const float*)d_in[3];
    const float* wk    = (const float*)d_in[4];
    const float* sk    = (const float*)d_in[5];
    const float* bk    = (const float*)d_in[6];
    const float* wv    = (const float*)d_in[7];
    const float* sv    = (const float*)d_in[8];
    const float* bv    = (const float*)d_in[9];
    const float* w_dw  = (const float*)d_in[10];
    const float* s_dw  = (const float*)d_in[11];
    const float* b_dw  = (const float*)d_in[12];
    const float* cov_s = (const float*)d_in[13];
    const float* cov_b = (const float*)d_in[14];
    const float* kv    = (const float*)d_in[15];
    const float* kv3   = (const float*)d_in[16];
    const float* w_pw  = (const float*)d_in[17];
    const float* s_pw  = (const float*)d_in[18];
    const float* b_pw  = (const float*)d_in[19];
    const float* w_row = (const float*)d_in[20];
    const float* s_row = (const float*)d_in[21];
    const float* b_row = (const float*)d_in[22];
    const float* w_col = (const float*)d_in[23];
    const float* s_col = (const float*)d_in[24];
    const float* b_col = (const float*)d_in[25];
    const float* w_proj= (const float*)d_in[26];
    const float* s_proj= (const float*)d_in[27];
    const float* b_proj= (const float*)d_in[28];
    const float* pe_rq = (const float*)d_in[29];
    const float* pe_rk = (const float*)d_in[30];
    const float* pe_cq = (const float*)d_in[31];
    const float* pe_ck = (const float*)d_in[32];
    float* out = (float*)d_out;

    char* wsb = (char*)d_ws;
    size_t off = 0;
    auto alloc = [&](size_t bytes) { char* p = wsb + off; off += (bytes + 255) & ~255UL; return p; };
    bf16*  qkv0   = (bf16*) alloc(67108864);    // (8,1024,4096) bf16
    bf16*  qkvpw  = (bf16*) alloc(16777216);    // (8,256,4096) bf16 raw pre-bn
    bf16*  x_t    = (bf16*) alloc(16777216);    // (8,4096,256) bf16
    bf16*  x1a    = (bf16*) alloc(4194304);     // (8,64,4096) bf16
    bf16*  x3a    = (bf16*) alloc(4194304);
    float* rowm   = (float*)alloc(2097152);     // (8,1024,64)
    float* colm   = (float*)alloc(2097152);
    float* atr    = (float*)alloc(1048576);     // (8,512,64)
    float* atc    = (float*)alloc(1048576);
    float* outr   = (float*)alloc(1048576);
    float* outc   = (float*)alloc(1048576);
    float* Wga    = (float*)alloc(1048576);     // (1024,256)
    float* beta   = (float*)alloc(4096);
    bf16*  Nv_t   = (bf16*) alloc(229376);      // (64,1792)
    bf16*  Nh_t   = (bf16*) alloc(229376);
    float* Cv     = (float*)alloc(1792);
    float* Ch     = (float*)alloc(1792);
    bf16*  Mv_t   = (bf16*) alloc(229376);      // (256,448)
    bf16*  Mh_t   = (bf16*) alloc(229376);
    bf16*  Wall   = (bf16*) alloc(524288);      // (1024,256)
    bf16*  wpw_bf = (bf16*) alloc(524288);      // (256,1024)
    bf16*  wproj_bf = (bf16*)alloc(262144);     // (256,512)
    float* sb_s   = (float*)alloc(4096);
    float* sb_b   = (float*)alloc(4096);
    float* kvT2a  = (float*)alloc(1835008);     // (1024,448)
    float* kvT2b  = (float*)alloc(1835008);
    if (off > ws_size) return;  // clean fail if workspace too small

    const long AB = 512L * 64;

    // ---- weight prep ----
    castw<<<2565, 256, 0, stream>>>(wq, wk, wv, sq, sk, sv, bq, bk, bv, w_pw, w_proj,
                                    Wall, wpw_bf, wproj_bf, sb_s, sb_b);
    cast_xt<<<dim3(64, 4, 8), 256, 0, stream>>>(x, x_t);
    build_wga<<<1024, 256, 0, stream>>>(wq, wk, wv, sq, sk, sv, bq, bk, bv, cov_s, cov_b, Wga, beta);
    build_N<<<448, 256, 0, stream>>>(kv,  Wga, Nv_t);
    build_N<<<448, 256, 0, stream>>>(kv3, Wga, Nh_t);
    build_C<<<7, 64, 0, stream>>>(kv,  beta, Cv);
    build_C<<<7, 64, 0, stream>>>(kv3, beta, Ch);
    kv_transpose<<<1792, 256, 0, stream>>>(kv,  kvT2a);
    kv_transpose<<<1792, 256, 0, stream>>>(kv3, kvT2b);
    build_M2<<<448, 256, 0, stream>>>(w_pw, kvT2a, Mv_t);
    build_M2<<<448, 256, 0, stream>>>(w_pw, kvT2b, Mh_t);

    // ---- qkv0 = bn(1x1 conv) via MFMA ----
    mfma_qkv<<<dim3(32, 8, 8), 256, 0, stream>>>(x_t, Wall, sb_s, sb_b, qkv0);

    // ---- squeeze attention ----
    meanrc<<<8192, 64, 0, stream>>>(qkv0, rowm, colm);
    attn_kernel<<<dim3(8, 8, 2), 256, 0, stream>>>(rowm, colm, pe_rq, pe_rk, pe_cq, pe_ck, atr, atc);
    gemm1x1<<<dim3(1, 8, 8), 256, 0, stream>>>(atr, AB, 0, w_row, s_row, b_row, outr, AB, 0, 512, 512, 64, 1, nullptr, nullptr, 0, 0, nullptr, 0, nullptr, nullptr);
    gemm1x1<<<dim3(1, 8, 8), 256, 0, stream>>>(atc, AB, 0, w_col, s_col, b_col, outc, AB, 0, 512, 512, 64, 1, nullptr, nullptr, 0, 0, nullptr, 0, nullptr, nullptr);

    // ---- stripe conv 1 (fused bn+qkv pre-contraction) + act_dn ----
    mstripe1<<<dim3(16, 8), 256, 0, stream>>>(x_t, Nv_t, Cv, x1a, 0);
    softmax_sp_bf<<<512, 256, 0, stream>>>(x1a);
    group_renorm_bf<<<1024, 256, 0, stream>>>(x1a);
    mstripe1<<<dim3(16, 8), 256, 0, stream>>>(x_t, Nh_t, Ch, x3a, 1);
    softmax_sp_bf<<<512, 256, 0, stream>>>(x3a);
    group_renorm_bf<<<1024, 256, 0, stream>>>(x3a);

    // ---- pw conv with fused dw3x3 (bn deferred) + stripe conv 2 via w_pw ----
    mfma_pw_dw<<<dim3(32, 2, 8), 256, 0, stream>>>(qkv0, wpw_bf, w_dw, s_dw, b_dw, qkvpw);
    mstripe2<<<dim3(32, 2, 8), 256, 0, stream>>>(x1a, Mv_t, qkvpw, 0);
    mstripe2<<<dim3(32, 2, 8), 256, 0, stream>>>(x3a, Mh_t, qkvpw, 1);

    // ---- final proj with fused epilogue ----
    mfma_proj<<<dim3(32, 2, 8), 256, 0, stream>>>(qkv0, wproj_bf, outr, outc,
                                                  s_proj, b_proj, qkvpw, s_pw, b_pw, out);
}